// Round 5
// baseline (38.129 us; speedup 1.0000x reference)
//
#include <hip/hip_runtime.h>
#include <hip/hip_bf16.h>
#include <math.h>

// ======================= compile-time Wigner 3j =======================
namespace cw {

struct CD { double re, im; };
constexpr CD cmul(CD a, CD b) { return CD{a.re*b.re - a.im*b.im, a.re*b.im + a.im*b.re}; }
constexpr CD cadd(CD a, CD b) { return CD{a.re + b.re, a.im + b.im}; }

template <int N> struct ArrD { double v[N] {}; };
template <int N> struct ArrC { CD v[N] {}; };

constexpr double csqrt_(double x) {
  if (x <= 0.0) return 0.0;
  double g = x > 1.0 ? x : 1.0;
  for (int i = 0; i < 200; ++i) g = 0.5 * (g + x / g);
  return g;
}

constexpr ArrD<32> make_fact() {
  ArrD<32> f{};
  f.v[0] = 1.0;
  for (int i = 1; i < 32; ++i) f.v[i] = f.v[i - 1] * (double)i;
  return f;
}
constexpr ArrD<32> FACT = make_fact();
static_assert(FACT.v[5] == 120.0, "factorial sanity");

constexpr double su2_cg(int j1, int j2, int j3, int m1, int m2, int m3) {
  if (m3 != m1 + m2) return 0.0;
  int vmin = 0;
  if (-j1 + j2 + m3 > vmin) vmin = -j1 + j2 + m3;
  if (-j1 + m1 > vmin) vmin = -j1 + m1;
  int vmax = j2 + j3 + m1;
  if (j3 - j1 + j2 < vmax) vmax = j3 - j1 + j2;
  if (j3 + m3 < vmax) vmax = j3 + m3;
  const double c = csqrt_((2.0 * j3 + 1.0) * FACT.v[j3 + j1 - j2] * FACT.v[j3 - j1 + j2] *
                          FACT.v[j1 + j2 - j3] * FACT.v[j3 + m3] * FACT.v[j3 - m3] /
                          (FACT.v[j1 + j2 + j3 + 1] * FACT.v[j1 - m1] * FACT.v[j1 + m1] *
                           FACT.v[j2 - m2] * FACT.v[j2 + m2]));
  double s = 0.0;
  for (int v = vmin; v <= vmax; ++v) {
    const double sg = ((v + j2 + m2) % 2 == 0) ? 1.0 : -1.0;
    s += sg * FACT.v[j2 + j3 + m1 - v] * FACT.v[j1 - m1 + v] /
         (FACT.v[v] * FACT.v[j3 - j1 + j2 - v] * FACT.v[j3 + m3 - v] * FACT.v[v + j1 - j2 - m3]);
  }
  return c * s;
}

template <int L> constexpr ArrC<(2 * L + 1) * (2 * L + 1)> real_basis() {
  constexpr int n = 2 * L + 1;
  ArrC<n * n> q{};
  const double s = 1.0 / csqrt_(2.0);
  for (int m = -L; m < 0; ++m) {
    q.v[(L + m) * n + (L - m)] = CD{s, 0.0};
    q.v[(L + m) * n + (L + m)] = CD{0.0, -s};
  }
  q.v[L * n + L] = CD{1.0, 0.0};
  for (int m = 1; m <= L; ++m) {
    const double sg = (m % 2 == 0) ? 1.0 : -1.0;
    q.v[(L + m) * n + (L + m)] = CD{sg * s, 0.0};
    q.v[(L + m) * n + (L - m)] = CD{0.0, sg * s};
  }
  CD ph = CD{1.0, 0.0};
  if (L % 4 == 1) ph = CD{0.0, -1.0};
  if (L % 4 == 2) ph = CD{-1.0, 0.0};
  if (L % 4 == 3) ph = CD{0.0, 1.0};
  for (int i = 0; i < n * n; ++i) q.v[i] = cmul(ph, q.v[i]);
  return q;
}

template <int L1, int L2, int L3>
constexpr ArrD<(2 * L1 + 1) * (2 * L2 + 1) * (2 * L3 + 1)> w3j_real() {
  constexpr int n1 = 2 * L1 + 1, n2 = 2 * L2 + 1, n3 = 2 * L3 + 1;
  const ArrC<n1 * n1> Q1 = real_basis<L1>();
  const ArrC<n2 * n2> Q2 = real_basis<L2>();
  const ArrC<n3 * n3> Q3 = real_basis<L3>();
  ArrC<n1 * n2 * n3> T1{};
  for (int a = 0; a < n1; ++a)
    for (int b = 0; b < n2; ++b) {
      const int m3 = (a - L1) + (b - L2);
      if (m3 < -L3 || m3 > L3) continue;
      const int c = L3 + m3;
      const double cg = su2_cg(L1, L2, L3, a - L1, b - L2, m3);
      if (cg == 0.0) continue;
      for (int k = 0; k < n3; ++k) {
        const CD q = Q3.v[k * n3 + c];
        if (q.re != 0.0 || q.im != 0.0)
          T1.v[(a * n2 + b) * n3 + k] = cadd(T1.v[(a * n2 + b) * n3 + k], CD{q.re * cg, -q.im * cg});
      }
    }
  ArrC<n1 * n2 * n3> T2{};
  for (int a = 0; a < n1; ++a)
    for (int b = 0; b < n2; ++b)
      for (int j = 0; j < n2; ++j) {
        const CD q = Q2.v[b * n2 + j];
        if (q.re == 0.0 && q.im == 0.0) continue;
        for (int k = 0; k < n3; ++k) {
          const CD t = T1.v[(a * n2 + b) * n3 + k];
          if (t.re != 0.0 || t.im != 0.0)
            T2.v[(a * n2 + j) * n3 + k] = cadd(T2.v[(a * n2 + j) * n3 + k], cmul(q, t));
        }
      }
  ArrD<n1 * n2 * n3> O{};
  for (int a = 0; a < n1; ++a)
    for (int i = 0; i < n1; ++i) {
      const CD q = Q1.v[a * n1 + i];
      if (q.re == 0.0 && q.im == 0.0) continue;
      for (int j = 0; j < n2; ++j)
        for (int k = 0; k < n3; ++k) {
          const CD t = T2.v[(a * n2 + j) * n3 + k];
          O.v[(i * n2 + j) * n3 + k] += q.re * t.re - q.im * t.im;
        }
    }
  double nrm2 = 0.0;
  for (int e = 0; e < n1 * n2 * n3; ++e) nrm2 += O.v[e] * O.v[e];
  const double inv = 1.0 / csqrt_(nrm2);
  for (int e = 0; e < n1 * n2 * n3; ++e) O.v[e] *= inv;
  return O;
}

constexpr ArrD<81>  W440 = w3j_real<4, 4, 0>();
constexpr ArrD<405> W442 = w3j_real<4, 4, 2>();
constexpr ArrD<169> W660 = w3j_real<6, 6, 0>();
constexpr ArrD<845> W662 = w3j_real<6, 6, 2>();
constexpr ArrD<585> W462 = w3j_real<4, 6, 2>();
constexpr ArrD<585> W642 = w3j_real<6, 4, 2>();
constexpr ArrD<75>  W221 = w3j_real<2, 2, 1>();

constexpr bool sym642() {
  for (int a = 0; a < 9; ++a)
    for (int b = 0; b < 13; ++b)
      for (int k = 0; k < 5; ++k) {
        const double d = W642.v[(b * 9 + a) * 5 + k] - W462.v[(a * 13 + b) * 5 + k];
        if (d > 1e-9 || d < -1e-9) return false;
      }
  return true;
}
static_assert(sym642(), "W642 != W462^T — basis fold invalid");

// compile-time check of the pair decode used in the kernel (lockstep guard)
constexpr bool decode_ok() {
  int idx = 0;
  for (int u = 0; u < 8; ++u)
    for (int v = u + 1; v < 8; ++v) {
      int U = 0, rem = idx;
      for (int uu = 0; uu < 7; ++uu)
        if (rem >= 7 - uu && U == uu) { rem -= 7 - uu; U = uu + 1; }
      const int V = U + 1 + rem;
      if (U != u || V != v) return false;
      ++idx;
    }
  return true;
}
static_assert(decode_ok(), "pair decode broken");

} // namespace cw

// ======================= fast atan2 (minimax, err ~1e-6 rad) =======================
__device__ __forceinline__ float fatan2(float y, float x) {
  const float ax = fabsf(x), ay = fabsf(y);
  const float mx = fmaxf(ax, ay), mn = fminf(ax, ay);
  const float a = mn * __builtin_amdgcn_rcpf(fmaxf(mx, 1e-38f));
  const float s = a * a;
  float r = fmaf(s, fmaf(s, fmaf(s, fmaf(s, fmaf(s, -0.0117212f, 0.05265332f),
                                         -0.11643287f), 0.19354346f), -0.33262347f), 0.99997726f);
  r *= a;
  if (ay > ax) r = 1.57079637f - r;
  if (x < 0.f) r = 3.14159274f - r;
  return (y < 0.f) ? -r : r;
}

// ======================= single fused kernel =======================
// Weight-only layer-2 coefficients recomputed per block into LDS by the first
// 168 threads. sc layout: sc[pair*6 + w*3 + pq], pair = upper-tri index (u<v),
// c = (wtt[u,v,w]-wtt[v,u,w]) * (a_p[u] a_q[v] - a_p[v] a_q[u]),
// basis p in {T44, T46(=T64), T66}, a_0=w44t, a_1=w46t+w64t, a_2=w66t.
__global__ __launch_bounds__(256, 4) void geo_euler(
    const float* __restrict__ feat,
    const float* __restrict__ w44s2, const float* __restrict__ w66s2,
    const float* __restrict__ w44t, const float* __restrict__ w46t,
    const float* __restrict__ w64t, const float* __restrict__ w66t,
    const float* __restrict__ wtt,
    float* __restrict__ out, int B)
{
  __shared__ float sc[168];
  const int tid = threadIdx.x;
  const int b = blockIdx.x * 256 + tid;

  if (tid < 168) {
    const int pair = tid / 6;
    const int slot = tid % 6;
    const int w = slot / 3;
    const int pq = slot % 3;
    // (U,V) with U<V from upper-tri pair index — lockstep-guarded decode
    int U = 0, rem = pair;
#pragma unroll
    for (int uu = 0; uu < 7; ++uu)
      if (rem >= 7 - uu && U == uu) { rem -= 7 - uu; U = uu + 1; }
    const int V = U + 1 + rem;
    const int p = (pq == 2) ? 1 : 0; // pq: 0->(0,1), 1->(0,2), 2->(1,2)
    const int q = (pq == 0) ? 1 : 2;
    const float a1U = w46t[U] + w64t[U], a1V = w46t[V] + w64t[V];
    const float apU = (p == 0) ? w44t[U] : a1U;
    const float apV = (p == 0) ? w44t[V] : a1V;
    const float aqU = (q == 1) ? a1U : w66t[U];
    const float aqV = (q == 1) ? a1V : w66t[V];
    const float Aw = wtt[(U * 8 + V) * 2 + w] - wtt[(V * 8 + U) * 2 + w];
    sc[tid] = Aw * (apU * aqV - apV * aqU);
  }
  __syncthreads();

  // features: 22 floats, 8-byte aligned rows -> 11x float2
  float f[22];
  {
    const float2* fp = reinterpret_cast<const float2*>(feat + (size_t)b * 22);
#pragma unroll
    for (int i = 0; i < 11; ++i) { const float2 t = fp[i]; f[2 * i] = t.x; f[2 * i + 1] = t.y; }
  }
  const float* f4 = f;
  const float* f6 = f + 9;

  float q44 = 0.f, q66 = 0.f;
  float T0[5] = {}, T1[5] = {}, T2[5] = {}; // T44, T46(=T64), T66

#pragma unroll
  for (int I = 0; I < 9; ++I)
#pragma unroll
    for (int J = I; J < 9; ++J) {
      const float p = f4[I] * f4[J];
      {
        const float c = (I == J) ? (float)cw::W440.v[I * 9 + J]
                                 : (float)(cw::W440.v[I * 9 + J] + cw::W440.v[J * 9 + I]);
        if (c != 0.f) q44 = fmaf(c, p, q44);
      }
#pragma unroll
      for (int K = 0; K < 5; ++K) {
        const float c = (I == J) ? (float)cw::W442.v[(I * 9 + J) * 5 + K]
                                 : (float)(cw::W442.v[(I * 9 + J) * 5 + K] + cw::W442.v[(J * 9 + I) * 5 + K]);
        if (c != 0.f) T0[K] = fmaf(c, p, T0[K]);
      }
    }

#pragma unroll
  for (int I = 0; I < 13; ++I)
#pragma unroll
    for (int J = I; J < 13; ++J) {
      const float p = f6[I] * f6[J];
      {
        const float c = (I == J) ? (float)cw::W660.v[I * 13 + J]
                                 : (float)(cw::W660.v[I * 13 + J] + cw::W660.v[J * 13 + I]);
        if (c != 0.f) q66 = fmaf(c, p, q66);
      }
#pragma unroll
      for (int K = 0; K < 5; ++K) {
        const float c = (I == J) ? (float)cw::W662.v[(I * 13 + J) * 5 + K]
                                 : (float)(cw::W662.v[(I * 13 + J) * 5 + K] + cw::W662.v[(J * 13 + I) * 5 + K]);
        if (c != 0.f) T2[K] = fmaf(c, p, T2[K]);
      }
    }

#pragma unroll
  for (int a = 0; a < 9; ++a)
#pragma unroll
    for (int bb = 0; bb < 13; ++bb) {
      const float p = f4[a] * f6[bb];
#pragma unroll
      for (int K = 0; K < 5; ++K) {
        const float c46 = (float)cw::W462.v[(a * 13 + bb) * 5 + K];
        if (c46 != 0.f) T1[K] = fmaf(c46, p, T1[K]);
      }
    }

  // gates g_u = sigmoid(C0 * (w44s2[8+u] q44 + w66s2[8+u] q66))
  float g[8];
#pragma unroll
  for (int u = 0; u < 8; ++u) {
    const float s = 0.70710678118654752f * fmaf(w44s2[8 + u], q44, w66s2[8 + u] * q66);
    g[u] = __builtin_amdgcn_rcpf(1.f + __expf(-s));
  }

  // S_w(pq) = sum_{u<v} sc[pair*6 + w*3 + pq] * g_u g_v   (LDS broadcast reads)
  float S00 = 0.f, S01 = 0.f, S02 = 0.f, S10 = 0.f, S11 = 0.f, S12 = 0.f;
  {
    int idx = 0;
#pragma unroll
    for (int u = 0; u < 8; ++u)
#pragma unroll
      for (int v = u + 1; v < 8; ++v) {
        const float Gp = g[u] * g[v];
        const float* cp = &sc[idx * 6];
        S00 = fmaf(cp[0], Gp, S00);
        S01 = fmaf(cp[1], Gp, S01);
        S02 = fmaf(cp[2], Gp, S02);
        S10 = fmaf(cp[3], Gp, S10);
        S11 = fmaf(cp[4], Gp, S11);
        S12 = fmaf(cp[5], Gp, S12);
        ++idx;
      }
  }

  // B_K(T_p,T_q): av_q = C221_K T_q (sparse), then dots
  float av1[3][5] = {}, av2[3][5] = {};
#pragma unroll
  for (int I = 0; I < 5; ++I)
#pragma unroll
    for (int J = 0; J < 5; ++J)
#pragma unroll
      for (int K = 0; K < 3; ++K) {
        const float c = (float)cw::W221.v[(I * 5 + J) * 3 + K];
        if (c != 0.f) {
          av1[K][I] = fmaf(c, T1[J], av1[K][I]);
          av2[K][I] = fmaf(c, T2[J], av2[K][I]);
        }
      }
  float v0[3], v1[3];
#pragma unroll
  for (int K = 0; K < 3; ++K) {
    float M0 = 0.f, M1 = 0.f, M2 = 0.f;
#pragma unroll
    for (int I = 0; I < 5; ++I) {
      M0 = fmaf(T0[I], av1[K][I], M0); // B_K(T0,T1)
      M1 = fmaf(T0[I], av2[K][I], M1); // B_K(T0,T2)
      M2 = fmaf(T1[I], av2[K][I], M2); // B_K(T1,T2)
    }
    v0[K] = fmaf(M0, S00, fmaf(M1, S01, M2 * S02));
    v1[K] = fmaf(M0, S10, fmaf(M1, S11, M2 * S12));
  }

  // Gram-Schmidt frame + Euler angles
  const float n0 = sqrtf(v0[0] * v0[0] + v0[1] * v0[1] + v0[2] * v0[2]);
  const float i0 = __builtin_amdgcn_rcpf(fmaxf(n0, 1e-6f));
  const float z0 = v0[0] * i0, z1 = v0[1] * i0, z2 = v0[2] * i0;
  const float dot = z0 * v1[0] + z1 * v1[1] + z2 * v1[2];
  const float xv0 = v1[0] - dot * z0, xv1 = v1[1] - dot * z1, xv2 = v1[2] - dot * z2;
  const float nx = sqrtf(xv0 * xv0 + xv1 * xv1 + xv2 * xv2);
  const float ix = __builtin_amdgcn_rcpf(fmaxf(nx, 1e-6f));
  const float x0 = xv0 * ix, x1 = xv1 * ix, x2 = xv2 * ix;
  const float y0 = z1 * x2 - z2 * x1;
  const float y1 = z2 * x0 - z0 * x2;
  const float y2 = z0 * x1 - z1 * x0;

  const float r22 = fminf(fmaxf(z2, -1.f), 1.f);
  const float sb = sqrtf(fmaxf(1.f - r22 * r22, 0.f)); // |sin(acos r22)|
  const float beta = fatan2(sb, r22);                  // acos(r22)
  const bool safe = sb > 1e-6f;
  const float alpha = safe ? fatan2(z1, z0) : 0.f;
  const float gamma = safe ? fatan2(y2, -x2) : fatan2(-y0, y1);

  if (b < B) {
    out[b] = alpha;
    out[B + b] = beta;
    out[2 * (size_t)B + b] = gamma;
    float* Ro = out + 3 * (size_t)B + (size_t)b * 9;
    Ro[0] = x0; Ro[1] = y0; Ro[2] = z0;
    Ro[3] = x1; Ro[4] = y1; Ro[5] = z1;
    Ro[6] = x2; Ro[7] = y2; Ro[8] = z2;
  }
}

extern "C" void kernel_launch(void* const* d_in, const int* in_sizes, int n_in,
                              void* d_out, int out_size, void* d_ws, size_t ws_size,
                              hipStream_t stream) {
  (void)n_in; (void)out_size; (void)d_ws; (void)ws_size;
  const float* feat  = (const float*)d_in[0];
  const float* w44s2 = (const float*)d_in[3];
  const float* w66s2 = (const float*)d_in[4];
  const float* w44t  = (const float*)d_in[7];
  const float* w46t  = (const float*)d_in[8];
  const float* w64t  = (const float*)d_in[9];
  const float* w66t  = (const float*)d_in[10];
  const float* wtt   = (const float*)d_in[16];
  float* out = (float*)d_out;
  const int B = in_sizes[0] / 22;
  geo_euler<<<(B + 255) / 256, 256, 0, stream>>>(feat, w44s2, w66s2,
                                                 w44t, w46t, w64t, w66t, wtt, out, B);
}

// Round 6
// 17.207 us; speedup vs baseline: 2.2159x; 2.2159x over previous
//
#include <hip/hip_runtime.h>
#include <hip/hip_bf16.h>
#include <math.h>

// ======================= compile-time Wigner 3j =======================
namespace cw {

struct CD { double re, im; };
constexpr CD cmul(CD a, CD b) { return CD{a.re*b.re - a.im*b.im, a.re*b.im + a.im*b.re}; }
constexpr CD cadd(CD a, CD b) { return CD{a.re + b.re, a.im + b.im}; }

template <int N> struct ArrD { double v[N] {}; };
template <int N> struct ArrC { CD v[N] {}; };

constexpr double csqrt_(double x) {
  if (x <= 0.0) return 0.0;
  double g = x > 1.0 ? x : 1.0;
  for (int i = 0; i < 200; ++i) g = 0.5 * (g + x / g);
  return g;
}

constexpr ArrD<32> make_fact() {
  ArrD<32> f{};
  f.v[0] = 1.0;
  for (int i = 1; i < 32; ++i) f.v[i] = f.v[i - 1] * (double)i;
  return f;
}
constexpr ArrD<32> FACT = make_fact();
static_assert(FACT.v[5] == 120.0, "factorial sanity");

constexpr double su2_cg(int j1, int j2, int j3, int m1, int m2, int m3) {
  if (m3 != m1 + m2) return 0.0;
  int vmin = 0;
  if (-j1 + j2 + m3 > vmin) vmin = -j1 + j2 + m3;
  if (-j1 + m1 > vmin) vmin = -j1 + m1;
  int vmax = j2 + j3 + m1;
  if (j3 - j1 + j2 < vmax) vmax = j3 - j1 + j2;
  if (j3 + m3 < vmax) vmax = j3 + m3;
  const double c = csqrt_((2.0 * j3 + 1.0) * FACT.v[j3 + j1 - j2] * FACT.v[j3 - j1 + j2] *
                          FACT.v[j1 + j2 - j3] * FACT.v[j3 + m3] * FACT.v[j3 - m3] /
                          (FACT.v[j1 + j2 + j3 + 1] * FACT.v[j1 - m1] * FACT.v[j1 + m1] *
                           FACT.v[j2 - m2] * FACT.v[j2 + m2]));
  double s = 0.0;
  for (int v = vmin; v <= vmax; ++v) {
    const double sg = ((v + j2 + m2) % 2 == 0) ? 1.0 : -1.0;
    s += sg * FACT.v[j2 + j3 + m1 - v] * FACT.v[j1 - m1 + v] /
         (FACT.v[v] * FACT.v[j3 - j1 + j2 - v] * FACT.v[j3 + m3 - v] * FACT.v[v + j1 - j2 - m3]);
  }
  return c * s;
}

template <int L> constexpr ArrC<(2 * L + 1) * (2 * L + 1)> real_basis() {
  constexpr int n = 2 * L + 1;
  ArrC<n * n> q{};
  const double s = 1.0 / csqrt_(2.0);
  for (int m = -L; m < 0; ++m) {
    q.v[(L + m) * n + (L - m)] = CD{s, 0.0};
    q.v[(L + m) * n + (L + m)] = CD{0.0, -s};
  }
  q.v[L * n + L] = CD{1.0, 0.0};
  for (int m = 1; m <= L; ++m) {
    const double sg = (m % 2 == 0) ? 1.0 : -1.0;
    q.v[(L + m) * n + (L + m)] = CD{sg * s, 0.0};
    q.v[(L + m) * n + (L - m)] = CD{0.0, sg * s};
  }
  CD ph = CD{1.0, 0.0};
  if (L % 4 == 1) ph = CD{0.0, -1.0};
  if (L % 4 == 2) ph = CD{-1.0, 0.0};
  if (L % 4 == 3) ph = CD{0.0, 1.0};
  for (int i = 0; i < n * n; ++i) q.v[i] = cmul(ph, q.v[i]);
  return q;
}

template <int L1, int L2, int L3>
constexpr ArrD<(2 * L1 + 1) * (2 * L2 + 1) * (2 * L3 + 1)> w3j_real() {
  constexpr int n1 = 2 * L1 + 1, n2 = 2 * L2 + 1, n3 = 2 * L3 + 1;
  const ArrC<n1 * n1> Q1 = real_basis<L1>();
  const ArrC<n2 * n2> Q2 = real_basis<L2>();
  const ArrC<n3 * n3> Q3 = real_basis<L3>();
  ArrC<n1 * n2 * n3> T1{};
  for (int a = 0; a < n1; ++a)
    for (int b = 0; b < n2; ++b) {
      const int m3 = (a - L1) + (b - L2);
      if (m3 < -L3 || m3 > L3) continue;
      const int c = L3 + m3;
      const double cg = su2_cg(L1, L2, L3, a - L1, b - L2, m3);
      if (cg == 0.0) continue;
      for (int k = 0; k < n3; ++k) {
        const CD q = Q3.v[k * n3 + c];
        if (q.re != 0.0 || q.im != 0.0)
          T1.v[(a * n2 + b) * n3 + k] = cadd(T1.v[(a * n2 + b) * n3 + k], CD{q.re * cg, -q.im * cg});
      }
    }
  ArrC<n1 * n2 * n3> T2{};
  for (int a = 0; a < n1; ++a)
    for (int b = 0; b < n2; ++b)
      for (int j = 0; j < n2; ++j) {
        const CD q = Q2.v[b * n2 + j];
        if (q.re == 0.0 && q.im == 0.0) continue;
        for (int k = 0; k < n3; ++k) {
          const CD t = T1.v[(a * n2 + b) * n3 + k];
          if (t.re != 0.0 || t.im != 0.0)
            T2.v[(a * n2 + j) * n3 + k] = cadd(T2.v[(a * n2 + j) * n3 + k], cmul(q, t));
        }
      }
  ArrD<n1 * n2 * n3> O{};
  for (int a = 0; a < n1; ++a)
    for (int i = 0; i < n1; ++i) {
      const CD q = Q1.v[a * n1 + i];
      if (q.re == 0.0 && q.im == 0.0) continue;
      for (int j = 0; j < n2; ++j)
        for (int k = 0; k < n3; ++k) {
          const CD t = T2.v[(a * n2 + j) * n3 + k];
          O.v[(i * n2 + j) * n3 + k] += q.re * t.re - q.im * t.im;
        }
    }
  double nrm2 = 0.0;
  for (int e = 0; e < n1 * n2 * n3; ++e) nrm2 += O.v[e] * O.v[e];
  const double inv = 1.0 / csqrt_(nrm2);
  for (int e = 0; e < n1 * n2 * n3; ++e) O.v[e] *= inv;
  return O;
}

constexpr ArrD<81>  W440 = w3j_real<4, 4, 0>();
constexpr ArrD<405> W442 = w3j_real<4, 4, 2>();
constexpr ArrD<169> W660 = w3j_real<6, 6, 0>();
constexpr ArrD<845> W662 = w3j_real<6, 6, 2>();
constexpr ArrD<585> W462 = w3j_real<4, 6, 2>();
constexpr ArrD<585> W642 = w3j_real<6, 4, 2>();
constexpr ArrD<75>  W221 = w3j_real<2, 2, 1>();

constexpr bool sym642() {
  for (int a = 0; a < 9; ++a)
    for (int b = 0; b < 13; ++b)
      for (int k = 0; k < 5; ++k) {
        const double d = W642.v[(b * 9 + a) * 5 + k] - W462.v[(a * 13 + b) * 5 + k];
        if (d > 1e-9 || d < -1e-9) return false;
      }
  return true;
}
static_assert(sym642(), "W642 != W462^T — basis fold invalid");

// compile-time check of the pair decode used in the kernel (lockstep guard)
constexpr bool decode_ok() {
  int idx = 0;
  for (int u = 0; u < 8; ++u)
    for (int v = u + 1; v < 8; ++v) {
      int U = 0, rem = idx;
      for (int uu = 0; uu < 7; ++uu)
        if (rem >= 7 - uu && U == uu) { rem -= 7 - uu; U = uu + 1; }
      const int V = U + 1 + rem;
      if (U != u || V != v) return false;
      ++idx;
    }
  return true;
}
static_assert(decode_ok(), "pair decode broken");

} // namespace cw

// ======================= fast atan2 (minimax, err ~1e-6 rad) =======================
__device__ __forceinline__ float fatan2(float y, float x) {
  const float ax = fabsf(x), ay = fabsf(y);
  const float mx = fmaxf(ax, ay), mn = fminf(ax, ay);
  const float a = mn * __builtin_amdgcn_rcpf(fmaxf(mx, 1e-38f));
  const float s = a * a;
  float r = fmaf(s, fmaf(s, fmaf(s, fmaf(s, fmaf(s, -0.0117212f, 0.05265332f),
                                         -0.11643287f), 0.19354346f), -0.33262347f), 0.99997726f);
  r *= a;
  if (ay > ax) r = 1.57079637f - r;
  if (x < 0.f) r = 3.14159274f - r;
  return (y < 0.f) ? -r : r;
}

// ======================= single fused kernel =======================
// Weight-only layer-2 coefficients recomputed per block into LDS by the first
// 168 threads. sc layout: sc[pair*6 + w*3 + pq], pair = upper-tri index (u<v),
// c = (wtt[u,v,w]-wtt[v,u,w]) * (a_p[u] a_q[v] - a_p[v] a_q[u]),
// basis p in {T44, T46(=T64), T66}, a_0=w44t, a_1=w46t+w64t, a_2=w66t.
// NOTE: plain __launch_bounds__(256) — R5 showed (256,4) caps VGPR at 64 and
// spills ~77 MB/launch to scratch (WRITE_SIZE 90 MB vs 12.6 ideal).
__global__ __launch_bounds__(256) void geo_euler(
    const float* __restrict__ feat,
    const float* __restrict__ w44s2, const float* __restrict__ w66s2,
    const float* __restrict__ w44t, const float* __restrict__ w46t,
    const float* __restrict__ w64t, const float* __restrict__ w66t,
    const float* __restrict__ wtt,
    float* __restrict__ out, int B)
{
  __shared__ float sc[168];
  const int tid = threadIdx.x;
  const int b = blockIdx.x * 256 + tid;

  if (tid < 168) {
    const int pair = tid / 6;
    const int slot = tid % 6;
    const int w = slot / 3;
    const int pq = slot % 3;
    // (U,V) with U<V from upper-tri pair index — lockstep-guarded decode
    int U = 0, rem = pair;
#pragma unroll
    for (int uu = 0; uu < 7; ++uu)
      if (rem >= 7 - uu && U == uu) { rem -= 7 - uu; U = uu + 1; }
    const int V = U + 1 + rem;
    const int p = (pq == 2) ? 1 : 0; // pq: 0->(0,1), 1->(0,2), 2->(1,2)
    const int q = (pq == 0) ? 1 : 2;
    const float a1U = w46t[U] + w64t[U], a1V = w46t[V] + w64t[V];
    const float apU = (p == 0) ? w44t[U] : a1U;
    const float apV = (p == 0) ? w44t[V] : a1V;
    const float aqU = (q == 1) ? a1U : w66t[U];
    const float aqV = (q == 1) ? a1V : w66t[V];
    const float Aw = wtt[(U * 8 + V) * 2 + w] - wtt[(V * 8 + U) * 2 + w];
    sc[tid] = Aw * (apU * aqV - apV * aqU);
  }
  __syncthreads();

  // features: 22 floats, 8-byte aligned rows -> 11x float2
  float f[22];
  {
    const float2* fp = reinterpret_cast<const float2*>(feat + (size_t)b * 22);
#pragma unroll
    for (int i = 0; i < 11; ++i) { const float2 t = fp[i]; f[2 * i] = t.x; f[2 * i + 1] = t.y; }
  }
  const float* f4 = f;
  const float* f6 = f + 9;

  float q44 = 0.f, q66 = 0.f;
  float T0[5] = {}, T1[5] = {}, T2[5] = {}; // T44, T46(=T64), T66

  // ---- 4x4 ----
#pragma unroll
  for (int I = 0; I < 9; ++I)
#pragma unroll
    for (int J = I; J < 9; ++J) {
      const float p = f4[I] * f4[J];
      {
        const float c = (I == J) ? (float)cw::W440.v[I * 9 + J]
                                 : (float)(cw::W440.v[I * 9 + J] + cw::W440.v[J * 9 + I]);
        if (c != 0.f) q44 = fmaf(c, p, q44);
      }
#pragma unroll
      for (int K = 0; K < 5; ++K) {
        const float c = (I == J) ? (float)cw::W442.v[(I * 9 + J) * 5 + K]
                                 : (float)(cw::W442.v[(I * 9 + J) * 5 + K] + cw::W442.v[(J * 9 + I) * 5 + K]);
        if (c != 0.f) T0[K] = fmaf(c, p, T0[K]);
      }
    }

  // ---- 4x6 (f4 dies after this loop — keeps peak live range lower) ----
#pragma unroll
  for (int a = 0; a < 9; ++a)
#pragma unroll
    for (int bb = 0; bb < 13; ++bb) {
      const float p = f4[a] * f6[bb];
#pragma unroll
      for (int K = 0; K < 5; ++K) {
        const float c46 = (float)cw::W462.v[(a * 13 + bb) * 5 + K];
        if (c46 != 0.f) T1[K] = fmaf(c46, p, T1[K]);
      }
    }

  // ---- 6x6 ----
#pragma unroll
  for (int I = 0; I < 13; ++I)
#pragma unroll
    for (int J = I; J < 13; ++J) {
      const float p = f6[I] * f6[J];
      {
        const float c = (I == J) ? (float)cw::W660.v[I * 13 + J]
                                 : (float)(cw::W660.v[I * 13 + J] + cw::W660.v[J * 13 + I]);
        if (c != 0.f) q66 = fmaf(c, p, q66);
      }
#pragma unroll
      for (int K = 0; K < 5; ++K) {
        const float c = (I == J) ? (float)cw::W662.v[(I * 13 + J) * 5 + K]
                                 : (float)(cw::W662.v[(I * 13 + J) * 5 + K] + cw::W662.v[(J * 13 + I) * 5 + K]);
        if (c != 0.f) T2[K] = fmaf(c, p, T2[K]);
      }
    }

  // gates g_u = sigmoid(C0 * (w44s2[8+u] q44 + w66s2[8+u] q66))
  float g[8];
#pragma unroll
  for (int u = 0; u < 8; ++u) {
    const float s = 0.70710678118654752f * fmaf(w44s2[8 + u], q44, w66s2[8 + u] * q66);
    g[u] = __builtin_amdgcn_rcpf(1.f + __expf(-s));
  }

  // S_w(pq) = sum_{u<v} sc[pair*6 + w*3 + pq] * g_u g_v   (LDS broadcast reads)
  float S00 = 0.f, S01 = 0.f, S02 = 0.f, S10 = 0.f, S11 = 0.f, S12 = 0.f;
  {
    int idx = 0;
#pragma unroll
    for (int u = 0; u < 8; ++u)
#pragma unroll
      for (int v = u + 1; v < 8; ++v) {
        const float Gp = g[u] * g[v];
        const float* cp = &sc[idx * 6];
        S00 = fmaf(cp[0], Gp, S00);
        S01 = fmaf(cp[1], Gp, S01);
        S02 = fmaf(cp[2], Gp, S02);
        S10 = fmaf(cp[3], Gp, S10);
        S11 = fmaf(cp[4], Gp, S11);
        S12 = fmaf(cp[5], Gp, S12);
        ++idx;
      }
  }

  // B_K(T_p,T_q): av_q = C221_K T_q (sparse), then dots
  float av1[3][5] = {}, av2[3][5] = {};
#pragma unroll
  for (int I = 0; I < 5; ++I)
#pragma unroll
    for (int J = 0; J < 5; ++J)
#pragma unroll
      for (int K = 0; K < 3; ++K) {
        const float c = (float)cw::W221.v[(I * 5 + J) * 3 + K];
        if (c != 0.f) {
          av1[K][I] = fmaf(c, T1[J], av1[K][I]);
          av2[K][I] = fmaf(c, T2[J], av2[K][I]);
        }
      }
  float v0[3], v1[3];
#pragma unroll
  for (int K = 0; K < 3; ++K) {
    float M0 = 0.f, M1 = 0.f, M2 = 0.f;
#pragma unroll
    for (int I = 0; I < 5; ++I) {
      M0 = fmaf(T0[I], av1[K][I], M0); // B_K(T0,T1)
      M1 = fmaf(T0[I], av2[K][I], M1); // B_K(T0,T2)
      M2 = fmaf(T1[I], av2[K][I], M2); // B_K(T1,T2)
    }
    v0[K] = fmaf(M0, S00, fmaf(M1, S01, M2 * S02));
    v1[K] = fmaf(M0, S10, fmaf(M1, S11, M2 * S12));
  }

  // Gram-Schmidt frame + Euler angles
  const float n0 = sqrtf(v0[0] * v0[0] + v0[1] * v0[1] + v0[2] * v0[2]);
  const float i0 = __builtin_amdgcn_rcpf(fmaxf(n0, 1e-6f));
  const float z0 = v0[0] * i0, z1 = v0[1] * i0, z2 = v0[2] * i0;
  const float dot = z0 * v1[0] + z1 * v1[1] + z2 * v1[2];
  const float xv0 = v1[0] - dot * z0, xv1 = v1[1] - dot * z1, xv2 = v1[2] - dot * z2;
  const float nx = sqrtf(xv0 * xv0 + xv1 * xv1 + xv2 * xv2);
  const float ix = __builtin_amdgcn_rcpf(fmaxf(nx, 1e-6f));
  const float x0 = xv0 * ix, x1 = xv1 * ix, x2 = xv2 * ix;
  const float y0 = z1 * x2 - z2 * x1;
  const float y1 = z2 * x0 - z0 * x2;
  const float y2 = z0 * x1 - z1 * x0;

  const float r22 = fminf(fmaxf(z2, -1.f), 1.f);
  const float sb = sqrtf(fmaxf(1.f - r22 * r22, 0.f)); // |sin(acos r22)|
  const float beta = fatan2(sb, r22);                  // acos(r22)
  const bool safe = sb > 1e-6f;
  const float alpha = safe ? fatan2(z1, z0) : 0.f;
  const float gamma = safe ? fatan2(y2, -x2) : fatan2(-y0, y1);

  if (b < B) {
    out[b] = alpha;
    out[B + b] = beta;
    out[2 * (size_t)B + b] = gamma;
    float* Ro = out + 3 * (size_t)B + (size_t)b * 9;
    Ro[0] = x0; Ro[1] = y0; Ro[2] = z0;
    Ro[3] = x1; Ro[4] = y1; Ro[5] = z1;
    Ro[6] = x2; Ro[7] = y2; Ro[8] = z2;
  }
}

extern "C" void kernel_launch(void* const* d_in, const int* in_sizes, int n_in,
                              void* d_out, int out_size, void* d_ws, size_t ws_size,
                              hipStream_t stream) {
  (void)n_in; (void)out_size; (void)d_ws; (void)ws_size;
  const float* feat  = (const float*)d_in[0];
  const float* w44s2 = (const float*)d_in[3];
  const float* w66s2 = (const float*)d_in[4];
  const float* w44t  = (const float*)d_in[7];
  const float* w46t  = (const float*)d_in[8];
  const float* w64t  = (const float*)d_in[9];
  const float* w66t  = (const float*)d_in[10];
  const float* wtt   = (const float*)d_in[16];
  float* out = (float*)d_out;
  const int B = in_sizes[0] / 22;
  geo_euler<<<(B + 255) / 256, 256, 0, stream>>>(feat, w44s2, w66s2,
                                                 w44t, w46t, w64t, w66t, wtt, out, B);
}

// Round 7
// 16.090 us; speedup vs baseline: 2.3697x; 1.0694x over previous
//
#include <hip/hip_runtime.h>
#include <hip/hip_bf16.h>
#include <math.h>

// ======================= compile-time Wigner 3j =======================
namespace cw {

struct CD { double re, im; };
constexpr CD cmul(CD a, CD b) { return CD{a.re*b.re - a.im*b.im, a.re*b.im + a.im*b.re}; }
constexpr CD cadd(CD a, CD b) { return CD{a.re + b.re, a.im + b.im}; }

template <int N> struct ArrD { double v[N] {}; };
template <int N> struct ArrC { CD v[N] {}; };

constexpr double csqrt_(double x) {
  if (x <= 0.0) return 0.0;
  double g = x > 1.0 ? x : 1.0;
  for (int i = 0; i < 200; ++i) g = 0.5 * (g + x / g);
  return g;
}

constexpr ArrD<32> make_fact() {
  ArrD<32> f{};
  f.v[0] = 1.0;
  for (int i = 1; i < 32; ++i) f.v[i] = f.v[i - 1] * (double)i;
  return f;
}
constexpr ArrD<32> FACT = make_fact();
static_assert(FACT.v[5] == 120.0, "factorial sanity");

constexpr double su2_cg(int j1, int j2, int j3, int m1, int m2, int m3) {
  if (m3 != m1 + m2) return 0.0;
  int vmin = 0;
  if (-j1 + j2 + m3 > vmin) vmin = -j1 + j2 + m3;
  if (-j1 + m1 > vmin) vmin = -j1 + m1;
  int vmax = j2 + j3 + m1;
  if (j3 - j1 + j2 < vmax) vmax = j3 - j1 + j2;
  if (j3 + m3 < vmax) vmax = j3 + m3;
  const double c = csqrt_((2.0 * j3 + 1.0) * FACT.v[j3 + j1 - j2] * FACT.v[j3 - j1 + j2] *
                          FACT.v[j1 + j2 - j3] * FACT.v[j3 + m3] * FACT.v[j3 - m3] /
                          (FACT.v[j1 + j2 + j3 + 1] * FACT.v[j1 - m1] * FACT.v[j1 + m1] *
                           FACT.v[j2 - m2] * FACT.v[j2 + m2]));
  double s = 0.0;
  for (int v = vmin; v <= vmax; ++v) {
    const double sg = ((v + j2 + m2) % 2 == 0) ? 1.0 : -1.0;
    s += sg * FACT.v[j2 + j3 + m1 - v] * FACT.v[j1 - m1 + v] /
         (FACT.v[v] * FACT.v[j3 - j1 + j2 - v] * FACT.v[j3 + m3 - v] * FACT.v[v + j1 - j2 - m3]);
  }
  return c * s;
}

template <int L> constexpr ArrC<(2 * L + 1) * (2 * L + 1)> real_basis() {
  constexpr int n = 2 * L + 1;
  ArrC<n * n> q{};
  const double s = 1.0 / csqrt_(2.0);
  for (int m = -L; m < 0; ++m) {
    q.v[(L + m) * n + (L - m)] = CD{s, 0.0};
    q.v[(L + m) * n + (L + m)] = CD{0.0, -s};
  }
  q.v[L * n + L] = CD{1.0, 0.0};
  for (int m = 1; m <= L; ++m) {
    const double sg = (m % 2 == 0) ? 1.0 : -1.0;
    q.v[(L + m) * n + (L + m)] = CD{sg * s, 0.0};
    q.v[(L + m) * n + (L - m)] = CD{0.0, sg * s};
  }
  CD ph = CD{1.0, 0.0};
  if (L % 4 == 1) ph = CD{0.0, -1.0};
  if (L % 4 == 2) ph = CD{-1.0, 0.0};
  if (L % 4 == 3) ph = CD{0.0, 1.0};
  for (int i = 0; i < n * n; ++i) q.v[i] = cmul(ph, q.v[i]);
  return q;
}

template <int L1, int L2, int L3>
constexpr ArrD<(2 * L1 + 1) * (2 * L2 + 1) * (2 * L3 + 1)> w3j_real() {
  constexpr int n1 = 2 * L1 + 1, n2 = 2 * L2 + 1, n3 = 2 * L3 + 1;
  const ArrC<n1 * n1> Q1 = real_basis<L1>();
  const ArrC<n2 * n2> Q2 = real_basis<L2>();
  const ArrC<n3 * n3> Q3 = real_basis<L3>();
  ArrC<n1 * n2 * n3> T1{};
  for (int a = 0; a < n1; ++a)
    for (int b = 0; b < n2; ++b) {
      const int m3 = (a - L1) + (b - L2);
      if (m3 < -L3 || m3 > L3) continue;
      const int c = L3 + m3;
      const double cg = su2_cg(L1, L2, L3, a - L1, b - L2, m3);
      if (cg == 0.0) continue;
      for (int k = 0; k < n3; ++k) {
        const CD q = Q3.v[k * n3 + c];
        if (q.re != 0.0 || q.im != 0.0)
          T1.v[(a * n2 + b) * n3 + k] = cadd(T1.v[(a * n2 + b) * n3 + k], CD{q.re * cg, -q.im * cg});
      }
    }
  ArrC<n1 * n2 * n3> T2{};
  for (int a = 0; a < n1; ++a)
    for (int b = 0; b < n2; ++b)
      for (int j = 0; j < n2; ++j) {
        const CD q = Q2.v[b * n2 + j];
        if (q.re == 0.0 && q.im == 0.0) continue;
        for (int k = 0; k < n3; ++k) {
          const CD t = T1.v[(a * n2 + b) * n3 + k];
          if (t.re != 0.0 || t.im != 0.0)
            T2.v[(a * n2 + j) * n3 + k] = cadd(T2.v[(a * n2 + j) * n3 + k], cmul(q, t));
        }
      }
  ArrD<n1 * n2 * n3> O{};
  for (int a = 0; a < n1; ++a)
    for (int i = 0; i < n1; ++i) {
      const CD q = Q1.v[a * n1 + i];
      if (q.re == 0.0 && q.im == 0.0) continue;
      for (int j = 0; j < n2; ++j)
        for (int k = 0; k < n3; ++k) {
          const CD t = T2.v[(a * n2 + j) * n3 + k];
          O.v[(i * n2 + j) * n3 + k] += q.re * t.re - q.im * t.im;
        }
    }
  double nrm2 = 0.0;
  for (int e = 0; e < n1 * n2 * n3; ++e) nrm2 += O.v[e] * O.v[e];
  const double inv = 1.0 / csqrt_(nrm2);
  for (int e = 0; e < n1 * n2 * n3; ++e) O.v[e] *= inv;
  return O;
}

constexpr ArrD<81>  W440 = w3j_real<4, 4, 0>();
constexpr ArrD<405> W442 = w3j_real<4, 4, 2>();
constexpr ArrD<169> W660 = w3j_real<6, 6, 0>();
constexpr ArrD<845> W662 = w3j_real<6, 6, 2>();
constexpr ArrD<585> W462 = w3j_real<4, 6, 2>();
constexpr ArrD<585> W642 = w3j_real<6, 4, 2>();
constexpr ArrD<75>  W221 = w3j_real<2, 2, 1>();

constexpr bool sym642() {
  for (int a = 0; a < 9; ++a)
    for (int b = 0; b < 13; ++b)
      for (int k = 0; k < 5; ++k) {
        const double d = W642.v[(b * 9 + a) * 5 + k] - W462.v[(a * 13 + b) * 5 + k];
        if (d > 1e-9 || d < -1e-9) return false;
      }
  return true;
}
static_assert(sym642(), "W642 != W462^T — basis fold invalid");

// compile-time check of the pair decode used in the kernel (lockstep guard)
constexpr bool decode_ok() {
  int idx = 0;
  for (int u = 0; u < 8; ++u)
    for (int v = u + 1; v < 8; ++v) {
      int U = 0, rem = idx;
      for (int uu = 0; uu < 7; ++uu)
        if (rem >= 7 - uu && U == uu) { rem -= 7 - uu; U = uu + 1; }
      const int V = U + 1 + rem;
      if (U != u || V != v) return false;
      ++idx;
    }
  return true;
}
static_assert(decode_ok(), "pair decode broken");

// upper-tri pair index -> (u,v) tables for the unrolled S-loop
struct Pairs { int u[28] {}; int v[28] {}; };
constexpr Pairs make_pairs() {
  Pairs p{};
  int i = 0;
  for (int u = 0; u < 8; ++u)
    for (int v = u + 1; v < 8; ++v) { p.u[i] = u; p.v[i] = v; ++i; }
  return p;
}
constexpr Pairs PP = make_pairs();

} // namespace cw

// ======================= fast atan2 (minimax, err ~1e-6 rad) =======================
__device__ __forceinline__ float fatan2(float y, float x) {
  const float ax = fabsf(x), ay = fabsf(y);
  const float mx = fmaxf(ax, ay), mn = fminf(ax, ay);
  const float a = mn * __builtin_amdgcn_rcpf(fmaxf(mx, 1e-38f));
  const float s = a * a;
  float r = fmaf(s, fmaf(s, fmaf(s, fmaf(s, fmaf(s, -0.0117212f, 0.05265332f),
                                         -0.11643287f), 0.19354346f), -0.33262347f), 0.99997726f);
  r *= a;
  if (ay > ax) r = 1.57079637f - r;
  if (x < 0.f) r = 3.14159274f - r;
  return (y < 0.f) ? -r : r;
}

// ======================= single fused kernel =======================
// Weight-only layer-2 coefficients recomputed per block into LDS by the first
// 168 threads. sc layout: sc[pair*6 + w*3 + pq], pair = upper-tri index (u<v),
// c = (wtt[u,v,w]-wtt[v,u,w]) * (a_p[u] a_q[v] - a_p[v] a_q[u]),
// basis p in {T44, T46(=T64), T66}, a_0=w44t, a_1=w46t+w64t, a_2=w66t.
// NOTES: plain __launch_bounds__(256) — (256,4) caps VGPR at 64 and spills
// ~77 MB/launch (R5). Barrier sits just before the S-loop (only reader of sc)
// so the contraction overlaps preamble + feature-load latency. S-loop reads
// sc as float4 (42 ds_read_b128 instead of 168 ds_read_b32).
__global__ __launch_bounds__(256) void geo_euler(
    const float* __restrict__ feat,
    const float* __restrict__ w44s2, const float* __restrict__ w66s2,
    const float* __restrict__ w44t, const float* __restrict__ w46t,
    const float* __restrict__ w64t, const float* __restrict__ w66t,
    const float* __restrict__ wtt,
    float* __restrict__ out, int B)
{
  __shared__ __align__(16) float sc[168];
  const int tid = threadIdx.x;
  const int b = blockIdx.x * 256 + tid;

  // issue feature loads FIRST — 11x float2; first use is the 44 loop, so the
  // preamble below runs while these are in flight
  float f[22];
  {
    const float2* fp = reinterpret_cast<const float2*>(feat + (size_t)b * 22);
#pragma unroll
    for (int i = 0; i < 11; ++i) { const float2 t = fp[i]; f[2 * i] = t.x; f[2 * i + 1] = t.y; }
  }

  if (tid < 168) {
    const int pair = tid / 6;
    const int slot = tid % 6;
    const int w = slot / 3;
    const int pq = slot % 3;
    // (U,V) with U<V from upper-tri pair index — lockstep-guarded decode
    int U = 0, rem = pair;
#pragma unroll
    for (int uu = 0; uu < 7; ++uu)
      if (rem >= 7 - uu && U == uu) { rem -= 7 - uu; U = uu + 1; }
    const int V = U + 1 + rem;
    const int p = (pq == 2) ? 1 : 0; // pq: 0->(0,1), 1->(0,2), 2->(1,2)
    const int q = (pq == 0) ? 1 : 2;
    const float a1U = w46t[U] + w64t[U], a1V = w46t[V] + w64t[V];
    const float apU = (p == 0) ? w44t[U] : a1U;
    const float apV = (p == 0) ? w44t[V] : a1V;
    const float aqU = (q == 1) ? a1U : w66t[U];
    const float aqV = (q == 1) ? a1V : w66t[V];
    const float Aw = wtt[(U * 8 + V) * 2 + w] - wtt[(V * 8 + U) * 2 + w];
    sc[tid] = Aw * (apU * aqV - apV * aqU);
  }

  const float* f4 = f;
  const float* f6 = f + 9;

  float q44 = 0.f, q66 = 0.f;
  float T0[5] = {}, T1[5] = {}, T2[5] = {}; // T44, T46(=T64), T66

  // ---- 4x4 ----
#pragma unroll
  for (int I = 0; I < 9; ++I)
#pragma unroll
    for (int J = I; J < 9; ++J) {
      const float p = f4[I] * f4[J];
      {
        const float c = (I == J) ? (float)cw::W440.v[I * 9 + J]
                                 : (float)(cw::W440.v[I * 9 + J] + cw::W440.v[J * 9 + I]);
        if (c != 0.f) q44 = fmaf(c, p, q44);
      }
#pragma unroll
      for (int K = 0; K < 5; ++K) {
        const float c = (I == J) ? (float)cw::W442.v[(I * 9 + J) * 5 + K]
                                 : (float)(cw::W442.v[(I * 9 + J) * 5 + K] + cw::W442.v[(J * 9 + I) * 5 + K]);
        if (c != 0.f) T0[K] = fmaf(c, p, T0[K]);
      }
    }

  // ---- 4x6 (f4 dies after this loop) ----
#pragma unroll
  for (int a = 0; a < 9; ++a)
#pragma unroll
    for (int bb = 0; bb < 13; ++bb) {
      const float p = f4[a] * f6[bb];
#pragma unroll
      for (int K = 0; K < 5; ++K) {
        const float c46 = (float)cw::W462.v[(a * 13 + bb) * 5 + K];
        if (c46 != 0.f) T1[K] = fmaf(c46, p, T1[K]);
      }
    }

  // ---- 6x6 ----
#pragma unroll
  for (int I = 0; I < 13; ++I)
#pragma unroll
    for (int J = I; J < 13; ++J) {
      const float p = f6[I] * f6[J];
      {
        const float c = (I == J) ? (float)cw::W660.v[I * 13 + J]
                                 : (float)(cw::W660.v[I * 13 + J] + cw::W660.v[J * 13 + I]);
        if (c != 0.f) q66 = fmaf(c, p, q66);
      }
#pragma unroll
      for (int K = 0; K < 5; ++K) {
        const float c = (I == J) ? (float)cw::W662.v[(I * 13 + J) * 5 + K]
                                 : (float)(cw::W662.v[(I * 13 + J) * 5 + K] + cw::W662.v[(J * 13 + I) * 5 + K]);
        if (c != 0.f) T2[K] = fmaf(c, p, T2[K]);
      }
    }

  // gates g_u = sigmoid(C0 * (w44s2[8+u] q44 + w66s2[8+u] q66))
  float g[8];
#pragma unroll
  for (int u = 0; u < 8; ++u) {
    const float s = 0.70710678118654752f * fmaf(w44s2[8 + u], q44, w66s2[8 + u] * q66);
    g[u] = __builtin_amdgcn_rcpf(1.f + __expf(-s));
  }

  // barrier here: everything above is independent of sc; only the S-loop reads it
  __syncthreads();

  // S_w(pq) = sum_{u<v} sc[pair*6 + w*3 + pq] * g_u g_v
  // read sc as float4: 2 pairs = 12 floats = 3 x ds_read_b128 (all 48B groups
  // are 16B-aligned)
  float S00 = 0.f, S01 = 0.f, S02 = 0.f, S10 = 0.f, S11 = 0.f, S12 = 0.f;
  {
    const float4* scv = reinterpret_cast<const float4*>(sc);
#pragma unroll
    for (int gp = 0; gp < 14; ++gp) {
      const float4 c0 = scv[gp * 3 + 0];
      const float4 c1 = scv[gp * 3 + 1];
      const float4 c2 = scv[gp * 3 + 2];
      const float Ga = g[cw::PP.u[2 * gp]] * g[cw::PP.v[2 * gp]];
      const float Gb = g[cw::PP.u[2 * gp + 1]] * g[cw::PP.v[2 * gp + 1]];
      S00 = fmaf(c0.x, Ga, S00); S01 = fmaf(c0.y, Ga, S01); S02 = fmaf(c0.z, Ga, S02);
      S10 = fmaf(c0.w, Ga, S10); S11 = fmaf(c1.x, Ga, S11); S12 = fmaf(c1.y, Ga, S12);
      S00 = fmaf(c1.z, Gb, S00); S01 = fmaf(c1.w, Gb, S01); S02 = fmaf(c2.x, Gb, S02);
      S10 = fmaf(c2.y, Gb, S10); S11 = fmaf(c2.z, Gb, S11); S12 = fmaf(c2.w, Gb, S12);
    }
  }

  // B_K(T_p,T_q): av_q = C221_K T_q (sparse), then dots
  float av1[3][5] = {}, av2[3][5] = {};
#pragma unroll
  for (int I = 0; I < 5; ++I)
#pragma unroll
    for (int J = 0; J < 5; ++J)
#pragma unroll
      for (int K = 0; K < 3; ++K) {
        const float c = (float)cw::W221.v[(I * 5 + J) * 3 + K];
        if (c != 0.f) {
          av1[K][I] = fmaf(c, T1[J], av1[K][I]);
          av2[K][I] = fmaf(c, T2[J], av2[K][I]);
        }
      }
  float v0[3], v1[3];
#pragma unroll
  for (int K = 0; K < 3; ++K) {
    float M0 = 0.f, M1 = 0.f, M2 = 0.f;
#pragma unroll
    for (int I = 0; I < 5; ++I) {
      M0 = fmaf(T0[I], av1[K][I], M0); // B_K(T0,T1)
      M1 = fmaf(T0[I], av2[K][I], M1); // B_K(T0,T2)
      M2 = fmaf(T1[I], av2[K][I], M2); // B_K(T1,T2)
    }
    v0[K] = fmaf(M0, S00, fmaf(M1, S01, M2 * S02));
    v1[K] = fmaf(M0, S10, fmaf(M1, S11, M2 * S12));
  }

  // Gram-Schmidt frame (rsq on squared norms — matches ref's max(n,1e-6) exactly
  // in the safe region: n<1e-6 <=> nsq<1e-12)
  const float nsq0 = v0[0] * v0[0] + v0[1] * v0[1] + v0[2] * v0[2];
  const float i0 = __builtin_amdgcn_rsqf(fmaxf(nsq0, 1e-12f));
  const float z0 = v0[0] * i0, z1 = v0[1] * i0, z2 = v0[2] * i0;
  const float dot = z0 * v1[0] + z1 * v1[1] + z2 * v1[2];
  const float xv0 = v1[0] - dot * z0, xv1 = v1[1] - dot * z1, xv2 = v1[2] - dot * z2;
  const float nsqx = xv0 * xv0 + xv1 * xv1 + xv2 * xv2;
  const float ix = __builtin_amdgcn_rsqf(fmaxf(nsqx, 1e-12f));
  const float x0 = xv0 * ix, x1 = xv1 * ix, x2 = xv2 * ix;
  const float y0 = z1 * x2 - z2 * x1;
  const float y1 = z2 * x0 - z0 * x2;
  const float y2 = z0 * x1 - z1 * x0;

  // beta = acos(clamp(z2)) via 4-term poly (A&S 4.4.45, |err|<=6.7e-5 rad)
  const float r22 = fminf(fmaxf(z2, -1.f), 1.f);
  const float axr = fabsf(r22);
  const float bp = fmaf(axr, fmaf(axr, fmaf(axr, -0.0187293f, 0.0742610f), -0.2121144f), 1.5707288f);
  const float bac = sqrtf(fmaxf(1.f - axr, 0.f)) * bp;
  const float beta = (r22 < 0.f) ? 3.14159274f - bac : bac;

  // safe <=> sin(beta)>1e-6 <=> 1-r22^2>1e-12 <=> |r22|<1 in fp32
  const bool safe = axr < 1.0f;
  float alpha = fatan2(z1, z0);
  float gamma = fatan2(y2, -x2);
  if (__ballot(!safe)) { // wave-uniform: skipped entirely for typical data
    if (!safe) { alpha = 0.f; gamma = fatan2(-y0, y1); }
  }

  if (b < B) {
    out[b] = alpha;
    out[B + b] = beta;
    out[2 * (size_t)B + b] = gamma;
    float* Ro = out + 3 * (size_t)B + (size_t)b * 9;
    Ro[0] = x0; Ro[1] = y0; Ro[2] = z0;
    Ro[3] = x1; Ro[4] = y1; Ro[5] = z1;
    Ro[6] = x2; Ro[7] = y2; Ro[8] = z2;
  }
}

extern "C" void kernel_launch(void* const* d_in, const int* in_sizes, int n_in,
                              void* d_out, int out_size, void* d_ws, size_t ws_size,
                              hipStream_t stream) {
  (void)n_in; (void)out_size; (void)d_ws; (void)ws_size;
  const float* feat  = (const float*)d_in[0];
  const float* w44s2 = (const float*)d_in[3];
  const float* w66s2 = (const float*)d_in[4];
  const float* w44t  = (const float*)d_in[7];
  const float* w46t  = (const float*)d_in[8];
  const float* w64t  = (const float*)d_in[9];
  const float* w66t  = (const float*)d_in[10];
  const float* wtt   = (const float*)d_in[16];
  float* out = (float*)d_out;
  const int B = in_sizes[0] / 22;
  geo_euler<<<(B + 255) / 256, 256, 0, stream>>>(feat, w44s2, w66s2,
                                                 w44t, w46t, w64t, w66t, wtt, out, B);
}

// Round 8
// 15.338 us; speedup vs baseline: 2.4859x; 1.0490x over previous
//
#include <hip/hip_runtime.h>
#include <hip/hip_bf16.h>
#include <math.h>

// ======================= compile-time Wigner 3j =======================
namespace cw {

struct CD { double re, im; };
constexpr CD cmul(CD a, CD b) { return CD{a.re*b.re - a.im*b.im, a.re*b.im + a.im*b.re}; }
constexpr CD cadd(CD a, CD b) { return CD{a.re + b.re, a.im + b.im}; }

template <int N> struct ArrD { double v[N] {}; };
template <int N> struct ArrC { CD v[N] {}; };

constexpr double csqrt_(double x) {
  if (x <= 0.0) return 0.0;
  double g = x > 1.0 ? x : 1.0;
  for (int i = 0; i < 200; ++i) g = 0.5 * (g + x / g);
  return g;
}

constexpr ArrD<32> make_fact() {
  ArrD<32> f{};
  f.v[0] = 1.0;
  for (int i = 1; i < 32; ++i) f.v[i] = f.v[i - 1] * (double)i;
  return f;
}
constexpr ArrD<32> FACT = make_fact();
static_assert(FACT.v[5] == 120.0, "factorial sanity");

constexpr double su2_cg(int j1, int j2, int j3, int m1, int m2, int m3) {
  if (m3 != m1 + m2) return 0.0;
  int vmin = 0;
  if (-j1 + j2 + m3 > vmin) vmin = -j1 + j2 + m3;
  if (-j1 + m1 > vmin) vmin = -j1 + m1;
  int vmax = j2 + j3 + m1;
  if (j3 - j1 + j2 < vmax) vmax = j3 - j1 + j2;
  if (j3 + m3 < vmax) vmax = j3 + m3;
  const double c = csqrt_((2.0 * j3 + 1.0) * FACT.v[j3 + j1 - j2] * FACT.v[j3 - j1 + j2] *
                          FACT.v[j1 + j2 - j3] * FACT.v[j3 + m3] * FACT.v[j3 - m3] /
                          (FACT.v[j1 + j2 + j3 + 1] * FACT.v[j1 - m1] * FACT.v[j1 + m1] *
                           FACT.v[j2 - m2] * FACT.v[j2 + m2]));
  double s = 0.0;
  for (int v = vmin; v <= vmax; ++v) {
    const double sg = ((v + j2 + m2) % 2 == 0) ? 1.0 : -1.0;
    s += sg * FACT.v[j2 + j3 + m1 - v] * FACT.v[j1 - m1 + v] /
         (FACT.v[v] * FACT.v[j3 - j1 + j2 - v] * FACT.v[j3 + m3 - v] * FACT.v[v + j1 - j2 - m3]);
  }
  return c * s;
}

template <int L> constexpr ArrC<(2 * L + 1) * (2 * L + 1)> real_basis() {
  constexpr int n = 2 * L + 1;
  ArrC<n * n> q{};
  const double s = 1.0 / csqrt_(2.0);
  for (int m = -L; m < 0; ++m) {
    q.v[(L + m) * n + (L - m)] = CD{s, 0.0};
    q.v[(L + m) * n + (L + m)] = CD{0.0, -s};
  }
  q.v[L * n + L] = CD{1.0, 0.0};
  for (int m = 1; m <= L; ++m) {
    const double sg = (m % 2 == 0) ? 1.0 : -1.0;
    q.v[(L + m) * n + (L + m)] = CD{sg * s, 0.0};
    q.v[(L + m) * n + (L - m)] = CD{0.0, sg * s};
  }
  CD ph = CD{1.0, 0.0};
  if (L % 4 == 1) ph = CD{0.0, -1.0};
  if (L % 4 == 2) ph = CD{-1.0, 0.0};
  if (L % 4 == 3) ph = CD{0.0, 1.0};
  for (int i = 0; i < n * n; ++i) q.v[i] = cmul(ph, q.v[i]);
  return q;
}

template <int L1, int L2, int L3>
constexpr ArrD<(2 * L1 + 1) * (2 * L2 + 1) * (2 * L3 + 1)> w3j_real() {
  constexpr int n1 = 2 * L1 + 1, n2 = 2 * L2 + 1, n3 = 2 * L3 + 1;
  const ArrC<n1 * n1> Q1 = real_basis<L1>();
  const ArrC<n2 * n2> Q2 = real_basis<L2>();
  const ArrC<n3 * n3> Q3 = real_basis<L3>();
  ArrC<n1 * n2 * n3> T1{};
  for (int a = 0; a < n1; ++a)
    for (int b = 0; b < n2; ++b) {
      const int m3 = (a - L1) + (b - L2);
      if (m3 < -L3 || m3 > L3) continue;
      const int c = L3 + m3;
      const double cg = su2_cg(L1, L2, L3, a - L1, b - L2, m3);
      if (cg == 0.0) continue;
      for (int k = 0; k < n3; ++k) {
        const CD q = Q3.v[k * n3 + c];
        if (q.re != 0.0 || q.im != 0.0)
          T1.v[(a * n2 + b) * n3 + k] = cadd(T1.v[(a * n2 + b) * n3 + k], CD{q.re * cg, -q.im * cg});
      }
    }
  ArrC<n1 * n2 * n3> T2{};
  for (int a = 0; a < n1; ++a)
    for (int b = 0; b < n2; ++b)
      for (int j = 0; j < n2; ++j) {
        const CD q = Q2.v[b * n2 + j];
        if (q.re == 0.0 && q.im == 0.0) continue;
        for (int k = 0; k < n3; ++k) {
          const CD t = T1.v[(a * n2 + b) * n3 + k];
          if (t.re != 0.0 || t.im != 0.0)
            T2.v[(a * n2 + j) * n3 + k] = cadd(T2.v[(a * n2 + j) * n3 + k], cmul(q, t));
        }
      }
  ArrD<n1 * n2 * n3> O{};
  for (int a = 0; a < n1; ++a)
    for (int i = 0; i < n1; ++i) {
      const CD q = Q1.v[a * n1 + i];
      if (q.re == 0.0 && q.im == 0.0) continue;
      for (int j = 0; j < n2; ++j)
        for (int k = 0; k < n3; ++k) {
          const CD t = T2.v[(a * n2 + j) * n3 + k];
          O.v[(i * n2 + j) * n3 + k] += q.re * t.re - q.im * t.im;
        }
    }
  double nrm2 = 0.0;
  for (int e = 0; e < n1 * n2 * n3; ++e) nrm2 += O.v[e] * O.v[e];
  const double inv = 1.0 / csqrt_(nrm2);
  for (int e = 0; e < n1 * n2 * n3; ++e) O.v[e] *= inv;
  return O;
}

constexpr ArrD<81>  W440 = w3j_real<4, 4, 0>();
constexpr ArrD<405> W442 = w3j_real<4, 4, 2>();
constexpr ArrD<169> W660 = w3j_real<6, 6, 0>();
constexpr ArrD<845> W662 = w3j_real<6, 6, 2>();
constexpr ArrD<585> W462 = w3j_real<4, 6, 2>();
constexpr ArrD<585> W642 = w3j_real<6, 4, 2>();
constexpr ArrD<75>  W221 = w3j_real<2, 2, 1>();

constexpr bool sym642() {
  for (int a = 0; a < 9; ++a)
    for (int b = 0; b < 13; ++b)
      for (int k = 0; k < 5; ++k) {
        const double d = W642.v[(b * 9 + a) * 5 + k] - W462.v[(a * 13 + b) * 5 + k];
        if (d > 1e-9 || d < -1e-9) return false;
      }
  return true;
}
static_assert(sym642(), "W642 != W462^T — basis fold invalid");

// compile-time check of the pair decode used in the kernel (lockstep guard)
constexpr bool decode_ok() {
  int idx = 0;
  for (int u = 0; u < 8; ++u)
    for (int v = u + 1; v < 8; ++v) {
      int U = 0, rem = idx;
      for (int uu = 0; uu < 7; ++uu)
        if (rem >= 7 - uu && U == uu) { rem -= 7 - uu; U = uu + 1; }
      const int V = U + 1 + rem;
      if (U != u || V != v) return false;
      ++idx;
    }
  return true;
}
static_assert(decode_ok(), "pair decode broken");

// upper-tri pair index -> (u,v) tables for the unrolled S-loop
struct Pairs { int u[28] {}; int v[28] {}; };
constexpr Pairs make_pairs() {
  Pairs p{};
  int i = 0;
  for (int u = 0; u < 8; ++u)
    for (int v = u + 1; v < 8; ++v) { p.u[i] = u; p.v[i] = v; ++i; }
  return p;
}
constexpr Pairs PP = make_pairs();

} // namespace cw

// ======================= fast atan2 (minimax, err ~1e-6 rad) =======================
__device__ __forceinline__ float fatan2(float y, float x) {
  const float ax = fabsf(x), ay = fabsf(y);
  const float mx = fmaxf(ax, ay), mn = fminf(ax, ay);
  const float a = mn * __builtin_amdgcn_rcpf(fmaxf(mx, 1e-38f));
  const float s = a * a;
  float r = fmaf(s, fmaf(s, fmaf(s, fmaf(s, fmaf(s, -0.0117212f, 0.05265332f),
                                         -0.11643287f), 0.19354346f), -0.33262347f), 0.99997726f);
  r *= a;
  if (ay > ax) r = 1.57079637f - r;
  if (x < 0.f) r = 3.14159274f - r;
  return (y < 0.f) ? -r : r;
}

// ======================= single fused kernel, 2 elements / thread =======================
// Thread t processes rows t and t+H (H = ceil(B/2)). Both feature sets load at
// the top: element A eats the HBM latency once; element B's loads land under
// A's ~2500-cycle compute, so B starts stall-free. 512 blocks — all resident,
// single generation, no per-generation re-stall.
// sc layout: sc[pair*6 + w*3 + pq] as in R7. Plain __launch_bounds__(256):
// (256,4) spills (R5).
__global__ __launch_bounds__(256) void geo_euler(
    const float* __restrict__ feat,
    const float* __restrict__ w44s2, const float* __restrict__ w66s2,
    const float* __restrict__ w44t, const float* __restrict__ w46t,
    const float* __restrict__ w64t, const float* __restrict__ w66t,
    const float* __restrict__ wtt,
    float* __restrict__ out, int B)
{
  __shared__ __align__(16) float sc[168];
  const int tid = threadIdx.x;
  const int H = (B + 1) >> 1;
  const int t = blockIdx.x * 256 + tid;
  const int bA = t;
  const int bB = (t + H < B) ? (t + H) : (B - 1);

  // issue ALL feature loads first (11+11 dwordx2); first use of fA waits only
  // on its own 11 (vmcnt counting), fB's stay in flight under A's compute
  float fA[22], fB[22];
  {
    const float2* pa = reinterpret_cast<const float2*>(feat + (size_t)bA * 22);
    const float2* pb = reinterpret_cast<const float2*>(feat + (size_t)bB * 22);
#pragma unroll
    for (int i = 0; i < 11; ++i) { const float2 v = pa[i]; fA[2 * i] = v.x; fA[2 * i + 1] = v.y; }
#pragma unroll
    for (int i = 0; i < 11; ++i) { const float2 v = pb[i]; fB[2 * i] = v.x; fB[2 * i + 1] = v.y; }
  }

  if (tid < 168) {
    const int pair = tid / 6;
    const int slot = tid % 6;
    const int w = slot / 3;
    const int pq = slot % 3;
    int U = 0, rem = pair;
#pragma unroll
    for (int uu = 0; uu < 7; ++uu)
      if (rem >= 7 - uu && U == uu) { rem -= 7 - uu; U = uu + 1; }
    const int V = U + 1 + rem;
    const int p = (pq == 2) ? 1 : 0; // pq: 0->(0,1), 1->(0,2), 2->(1,2)
    const int q = (pq == 0) ? 1 : 2;
    const float a1U = w46t[U] + w64t[U], a1V = w46t[V] + w64t[V];
    const float apU = (p == 0) ? w44t[U] : a1U;
    const float apV = (p == 0) ? w44t[V] : a1V;
    const float aqU = (q == 1) ? a1U : w66t[U];
    const float aqV = (q == 1) ? a1V : w66t[V];
    const float Aw = wtt[(U * 8 + V) * 2 + w] - wtt[(V * 8 + U) * 2 + w];
    sc[tid] = Aw * (apU * aqV - apV * aqU);
  }
  __syncthreads();

  auto process = [&](const float* __restrict__ f, int b) __attribute__((always_inline)) {
    const float* f4 = f;
    const float* f6 = f + 9;

    float q44 = 0.f, q66 = 0.f;
    float T0[5] = {}, T1[5] = {}, T2[5] = {}; // T44, T46(=T64), T66

    // ---- 4x4 ----
#pragma unroll
    for (int I = 0; I < 9; ++I)
#pragma unroll
      for (int J = I; J < 9; ++J) {
        const float p = f4[I] * f4[J];
        {
          const float c = (I == J) ? (float)cw::W440.v[I * 9 + J]
                                   : (float)(cw::W440.v[I * 9 + J] + cw::W440.v[J * 9 + I]);
          if (c != 0.f) q44 = fmaf(c, p, q44);
        }
#pragma unroll
        for (int K = 0; K < 5; ++K) {
          const float c = (I == J) ? (float)cw::W442.v[(I * 9 + J) * 5 + K]
                                   : (float)(cw::W442.v[(I * 9 + J) * 5 + K] + cw::W442.v[(J * 9 + I) * 5 + K]);
          if (c != 0.f) T0[K] = fmaf(c, p, T0[K]);
        }
      }

    // ---- 4x6 ----
#pragma unroll
    for (int a = 0; a < 9; ++a)
#pragma unroll
      for (int bb = 0; bb < 13; ++bb) {
        const float p = f4[a] * f6[bb];
#pragma unroll
        for (int K = 0; K < 5; ++K) {
          const float c46 = (float)cw::W462.v[(a * 13 + bb) * 5 + K];
          if (c46 != 0.f) T1[K] = fmaf(c46, p, T1[K]);
        }
      }

    // ---- 6x6 ----
#pragma unroll
    for (int I = 0; I < 13; ++I)
#pragma unroll
      for (int J = I; J < 13; ++J) {
        const float p = f6[I] * f6[J];
        {
          const float c = (I == J) ? (float)cw::W660.v[I * 13 + J]
                                   : (float)(cw::W660.v[I * 13 + J] + cw::W660.v[J * 13 + I]);
          if (c != 0.f) q66 = fmaf(c, p, q66);
        }
#pragma unroll
        for (int K = 0; K < 5; ++K) {
          const float c = (I == J) ? (float)cw::W662.v[(I * 13 + J) * 5 + K]
                                   : (float)(cw::W662.v[(I * 13 + J) * 5 + K] + cw::W662.v[(J * 13 + I) * 5 + K]);
          if (c != 0.f) T2[K] = fmaf(c, p, T2[K]);
        }
      }

    // gates g_u = sigmoid(C0 * (w44s2[8+u] q44 + w66s2[8+u] q66))
    float g[8];
#pragma unroll
    for (int u = 0; u < 8; ++u) {
      const float s = 0.70710678118654752f * fmaf(w44s2[8 + u], q44, w66s2[8 + u] * q66);
      g[u] = __builtin_amdgcn_rcpf(1.f + __expf(-s));
    }

    // S_w(pq) = sum_{u<v} sc[pair*6 + w*3 + pq] * g_u g_v  (float4 LDS reads)
    float S00 = 0.f, S01 = 0.f, S02 = 0.f, S10 = 0.f, S11 = 0.f, S12 = 0.f;
    {
      const float4* scv = reinterpret_cast<const float4*>(sc);
#pragma unroll
      for (int gp = 0; gp < 14; ++gp) {
        const float4 c0 = scv[gp * 3 + 0];
        const float4 c1 = scv[gp * 3 + 1];
        const float4 c2 = scv[gp * 3 + 2];
        const float Ga = g[cw::PP.u[2 * gp]] * g[cw::PP.v[2 * gp]];
        const float Gb = g[cw::PP.u[2 * gp + 1]] * g[cw::PP.v[2 * gp + 1]];
        S00 = fmaf(c0.x, Ga, S00); S01 = fmaf(c0.y, Ga, S01); S02 = fmaf(c0.z, Ga, S02);
        S10 = fmaf(c0.w, Ga, S10); S11 = fmaf(c1.x, Ga, S11); S12 = fmaf(c1.y, Ga, S12);
        S00 = fmaf(c1.z, Gb, S00); S01 = fmaf(c1.w, Gb, S01); S02 = fmaf(c2.x, Gb, S02);
        S10 = fmaf(c2.y, Gb, S10); S11 = fmaf(c2.z, Gb, S11); S12 = fmaf(c2.w, Gb, S12);
      }
    }

    // B_K(T_p,T_q): av_q = C221_K T_q (sparse), then dots
    float av1[3][5] = {}, av2[3][5] = {};
#pragma unroll
    for (int I = 0; I < 5; ++I)
#pragma unroll
      for (int J = 0; J < 5; ++J)
#pragma unroll
        for (int K = 0; K < 3; ++K) {
          const float c = (float)cw::W221.v[(I * 5 + J) * 3 + K];
          if (c != 0.f) {
            av1[K][I] = fmaf(c, T1[J], av1[K][I]);
            av2[K][I] = fmaf(c, T2[J], av2[K][I]);
          }
        }
    float v0[3], v1[3];
#pragma unroll
    for (int K = 0; K < 3; ++K) {
      float M0 = 0.f, M1 = 0.f, M2 = 0.f;
#pragma unroll
      for (int I = 0; I < 5; ++I) {
        M0 = fmaf(T0[I], av1[K][I], M0); // B_K(T0,T1)
        M1 = fmaf(T0[I], av2[K][I], M1); // B_K(T0,T2)
        M2 = fmaf(T1[I], av2[K][I], M2); // B_K(T1,T2)
      }
      v0[K] = fmaf(M0, S00, fmaf(M1, S01, M2 * S02));
      v1[K] = fmaf(M0, S10, fmaf(M1, S11, M2 * S12));
    }

    // Gram-Schmidt frame (rsq on squared norms)
    const float nsq0 = v0[0] * v0[0] + v0[1] * v0[1] + v0[2] * v0[2];
    const float i0 = __builtin_amdgcn_rsqf(fmaxf(nsq0, 1e-12f));
    const float z0 = v0[0] * i0, z1 = v0[1] * i0, z2 = v0[2] * i0;
    const float dot = z0 * v1[0] + z1 * v1[1] + z2 * v1[2];
    const float xv0 = v1[0] - dot * z0, xv1 = v1[1] - dot * z1, xv2 = v1[2] - dot * z2;
    const float nsqx = xv0 * xv0 + xv1 * xv1 + xv2 * xv2;
    const float ix = __builtin_amdgcn_rsqf(fmaxf(nsqx, 1e-12f));
    const float x0 = xv0 * ix, x1 = xv1 * ix, x2 = xv2 * ix;
    const float y0 = z1 * x2 - z2 * x1;
    const float y1 = z2 * x0 - z0 * x2;
    const float y2 = z0 * x1 - z1 * x0;

    // beta = acos(clamp(z2)) via 4-term poly (|err|<=6.7e-5 rad)
    const float r22 = fminf(fmaxf(z2, -1.f), 1.f);
    const float axr = fabsf(r22);
    const float bp = fmaf(axr, fmaf(axr, fmaf(axr, -0.0187293f, 0.0742610f), -0.2121144f), 1.5707288f);
    const float bac = sqrtf(fmaxf(1.f - axr, 0.f)) * bp;
    const float beta = (r22 < 0.f) ? 3.14159274f - bac : bac;

    const bool safe = axr < 1.0f;
    float alpha = fatan2(z1, z0);
    float gamma = fatan2(y2, -x2);
    if (__ballot(!safe)) {
      if (!safe) { alpha = 0.f; gamma = fatan2(-y0, y1); }
    }

    if (b < B) {
      out[b] = alpha;
      out[B + b] = beta;
      out[2 * (size_t)B + b] = gamma;
      float* Ro = out + 3 * (size_t)B + (size_t)b * 9;
      Ro[0] = x0; Ro[1] = y0; Ro[2] = z0;
      Ro[3] = x1; Ro[4] = y1; Ro[5] = z1;
      Ro[6] = x2; Ro[7] = y2; Ro[8] = z2;
    }
  };

  process(fA, bA);
  if (t + H < B) process(fB, t + H);
}

extern "C" void kernel_launch(void* const* d_in, const int* in_sizes, int n_in,
                              void* d_out, int out_size, void* d_ws, size_t ws_size,
                              hipStream_t stream) {
  (void)n_in; (void)out_size; (void)d_ws; (void)ws_size;
  const float* feat  = (const float*)d_in[0];
  const float* w44s2 = (const float*)d_in[3];
  const float* w66s2 = (const float*)d_in[4];
  const float* w44t  = (const float*)d_in[7];
  const float* w46t  = (const float*)d_in[8];
  const float* w64t  = (const float*)d_in[9];
  const float* w66t  = (const float*)d_in[10];
  const float* wtt   = (const float*)d_in[16];
  float* out = (float*)d_out;
  const int B = in_sizes[0] / 22;
  const int H = (B + 1) >> 1;
  geo_euler<<<(H + 255) / 256, 256, 0, stream>>>(feat, w44s2, w66s2,
                                                 w44t, w46t, w64t, w66t, wtt, out, B);
}

// Round 9
// 15.173 us; speedup vs baseline: 2.5130x; 1.0109x over previous
//
#include <hip/hip_runtime.h>
#include <hip/hip_bf16.h>
#include <math.h>

// ======================= compile-time Wigner 3j =======================
namespace cw {

struct CD { double re, im; };
constexpr CD cmul(CD a, CD b) { return CD{a.re*b.re - a.im*b.im, a.re*b.im + a.im*b.re}; }
constexpr CD cadd(CD a, CD b) { return CD{a.re + b.re, a.im + b.im}; }

template <int N> struct ArrD { double v[N] {}; };
template <int N> struct ArrC { CD v[N] {}; };

constexpr double csqrt_(double x) {
  if (x <= 0.0) return 0.0;
  double g = x > 1.0 ? x : 1.0;
  for (int i = 0; i < 200; ++i) g = 0.5 * (g + x / g);
  return g;
}

constexpr ArrD<32> make_fact() {
  ArrD<32> f{};
  f.v[0] = 1.0;
  for (int i = 1; i < 32; ++i) f.v[i] = f.v[i - 1] * (double)i;
  return f;
}
constexpr ArrD<32> FACT = make_fact();
static_assert(FACT.v[5] == 120.0, "factorial sanity");

constexpr double su2_cg(int j1, int j2, int j3, int m1, int m2, int m3) {
  if (m3 != m1 + m2) return 0.0;
  int vmin = 0;
  if (-j1 + j2 + m3 > vmin) vmin = -j1 + j2 + m3;
  if (-j1 + m1 > vmin) vmin = -j1 + m1;
  int vmax = j2 + j3 + m1;
  if (j3 - j1 + j2 < vmax) vmax = j3 - j1 + j2;
  if (j3 + m3 < vmax) vmax = j3 + m3;
  const double c = csqrt_((2.0 * j3 + 1.0) * FACT.v[j3 + j1 - j2] * FACT.v[j3 - j1 + j2] *
                          FACT.v[j1 + j2 - j3] * FACT.v[j3 + m3] * FACT.v[j3 - m3] /
                          (FACT.v[j1 + j2 + j3 + 1] * FACT.v[j1 - m1] * FACT.v[j1 + m1] *
                           FACT.v[j2 - m2] * FACT.v[j2 + m2]));
  double s = 0.0;
  for (int v = vmin; v <= vmax; ++v) {
    const double sg = ((v + j2 + m2) % 2 == 0) ? 1.0 : -1.0;
    s += sg * FACT.v[j2 + j3 + m1 - v] * FACT.v[j1 - m1 + v] /
         (FACT.v[v] * FACT.v[j3 - j1 + j2 - v] * FACT.v[j3 + m3 - v] * FACT.v[v + j1 - j2 - m3]);
  }
  return c * s;
}

template <int L> constexpr ArrC<(2 * L + 1) * (2 * L + 1)> real_basis() {
  constexpr int n = 2 * L + 1;
  ArrC<n * n> q{};
  const double s = 1.0 / csqrt_(2.0);
  for (int m = -L; m < 0; ++m) {
    q.v[(L + m) * n + (L - m)] = CD{s, 0.0};
    q.v[(L + m) * n + (L + m)] = CD{0.0, -s};
  }
  q.v[L * n + L] = CD{1.0, 0.0};
  for (int m = 1; m <= L; ++m) {
    const double sg = (m % 2 == 0) ? 1.0 : -1.0;
    q.v[(L + m) * n + (L + m)] = CD{sg * s, 0.0};
    q.v[(L + m) * n + (L - m)] = CD{0.0, sg * s};
  }
  CD ph = CD{1.0, 0.0};
  if (L % 4 == 1) ph = CD{0.0, -1.0};
  if (L % 4 == 2) ph = CD{-1.0, 0.0};
  if (L % 4 == 3) ph = CD{0.0, 1.0};
  for (int i = 0; i < n * n; ++i) q.v[i] = cmul(ph, q.v[i]);
  return q;
}

template <int L1, int L2, int L3>
constexpr ArrD<(2 * L1 + 1) * (2 * L2 + 1) * (2 * L3 + 1)> w3j_real() {
  constexpr int n1 = 2 * L1 + 1, n2 = 2 * L2 + 1, n3 = 2 * L3 + 1;
  const ArrC<n1 * n1> Q1 = real_basis<L1>();
  const ArrC<n2 * n2> Q2 = real_basis<L2>();
  const ArrC<n3 * n3> Q3 = real_basis<L3>();
  ArrC<n1 * n2 * n3> T1{};
  for (int a = 0; a < n1; ++a)
    for (int b = 0; b < n2; ++b) {
      const int m3 = (a - L1) + (b - L2);
      if (m3 < -L3 || m3 > L3) continue;
      const int c = L3 + m3;
      const double cg = su2_cg(L1, L2, L3, a - L1, b - L2, m3);
      if (cg == 0.0) continue;
      for (int k = 0; k < n3; ++k) {
        const CD q = Q3.v[k * n3 + c];
        if (q.re != 0.0 || q.im != 0.0)
          T1.v[(a * n2 + b) * n3 + k] = cadd(T1.v[(a * n2 + b) * n3 + k], CD{q.re * cg, -q.im * cg});
      }
    }
  ArrC<n1 * n2 * n3> T2{};
  for (int a = 0; a < n1; ++a)
    for (int b = 0; b < n2; ++b)
      for (int j = 0; j < n2; ++j) {
        const CD q = Q2.v[b * n2 + j];
        if (q.re == 0.0 && q.im == 0.0) continue;
        for (int k = 0; k < n3; ++k) {
          const CD t = T1.v[(a * n2 + b) * n3 + k];
          if (t.re != 0.0 || t.im != 0.0)
            T2.v[(a * n2 + j) * n3 + k] = cadd(T2.v[(a * n2 + j) * n3 + k], cmul(q, t));
        }
      }
  ArrD<n1 * n2 * n3> O{};
  for (int a = 0; a < n1; ++a)
    for (int i = 0; i < n1; ++i) {
      const CD q = Q1.v[a * n1 + i];
      if (q.re == 0.0 && q.im == 0.0) continue;
      for (int j = 0; j < n2; ++j)
        for (int k = 0; k < n3; ++k) {
          const CD t = T2.v[(a * n2 + j) * n3 + k];
          O.v[(i * n2 + j) * n3 + k] += q.re * t.re - q.im * t.im;
        }
    }
  double nrm2 = 0.0;
  for (int e = 0; e < n1 * n2 * n3; ++e) nrm2 += O.v[e] * O.v[e];
  const double inv = 1.0 / csqrt_(nrm2);
  for (int e = 0; e < n1 * n2 * n3; ++e) O.v[e] *= inv;
  return O;
}

constexpr ArrD<81>  W440 = w3j_real<4, 4, 0>();
constexpr ArrD<405> W442 = w3j_real<4, 4, 2>();
constexpr ArrD<169> W660 = w3j_real<6, 6, 0>();
constexpr ArrD<845> W662 = w3j_real<6, 6, 2>();
constexpr ArrD<585> W462 = w3j_real<4, 6, 2>();
constexpr ArrD<585> W642 = w3j_real<6, 4, 2>();
constexpr ArrD<75>  W221 = w3j_real<2, 2, 1>();

constexpr bool sym642() {
  for (int a = 0; a < 9; ++a)
    for (int b = 0; b < 13; ++b)
      for (int k = 0; k < 5; ++k) {
        const double d = W642.v[(b * 9 + a) * 5 + k] - W462.v[(a * 13 + b) * 5 + k];
        if (d > 1e-9 || d < -1e-9) return false;
      }
  return true;
}
static_assert(sym642(), "W642 != W462^T — basis fold invalid");

// compile-time check of the pair decode used in the kernel (lockstep guard)
constexpr bool decode_ok() {
  int idx = 0;
  for (int u = 0; u < 8; ++u)
    for (int v = u + 1; v < 8; ++v) {
      int U = 0, rem = idx;
      for (int uu = 0; uu < 7; ++uu)
        if (rem >= 7 - uu && U == uu) { rem -= 7 - uu; U = uu + 1; }
      const int V = U + 1 + rem;
      if (U != u || V != v) return false;
      ++idx;
    }
  return true;
}
static_assert(decode_ok(), "pair decode broken");

// upper-tri pair index -> (u,v) tables for the unrolled S-loop
struct Pairs { int u[28] {}; int v[28] {}; };
constexpr Pairs make_pairs() {
  Pairs p{};
  int i = 0;
  for (int u = 0; u < 8; ++u)
    for (int v = u + 1; v < 8; ++v) { p.u[i] = u; p.v[i] = v; ++i; }
  return p;
}
constexpr Pairs PP = make_pairs();

} // namespace cw

// ======================= fast atan2 (minimax, err ~1e-6 rad) =======================
__device__ __forceinline__ float fatan2(float y, float x) {
  const float ax = fabsf(x), ay = fabsf(y);
  const float mx = fmaxf(ax, ay), mn = fminf(ax, ay);
  const float a = mn * __builtin_amdgcn_rcpf(fmaxf(mx, 1e-38f));
  const float s = a * a;
  float r = fmaf(s, fmaf(s, fmaf(s, fmaf(s, fmaf(s, -0.0117212f, 0.05265332f),
                                         -0.11643287f), 0.19354346f), -0.33262347f), 0.99997726f);
  r *= a;
  if (ay > ax) r = 1.57079637f - r;
  if (x < 0.f) r = 3.14159274f - r;
  return (y < 0.f) ? -r : r;
}

// ======================= single fused kernel, 2 elements / thread =======================
// Thread t processes rows t and t+H (H = ceil(B/2)).
// Element B's feature load is DEFERRED to mid-element-A (after the 4x6 loop,
// where f4A dies): shrinks peak VGPR live-set while A's remaining ~700
// instructions still cover the HBM latency.
// __launch_bounds__(256,2): cap VGPR at 256 -> guarantee >=2 waves/SIMD.
// ((256,4) forced 64 VGPR + 77MB spill in R5 — do not revisit.)
__global__ __launch_bounds__(256, 2) void geo_euler(
    const float* __restrict__ feat,
    const float* __restrict__ w44s2, const float* __restrict__ w66s2,
    const float* __restrict__ w44t, const float* __restrict__ w46t,
    const float* __restrict__ w64t, const float* __restrict__ w66t,
    const float* __restrict__ wtt,
    float* __restrict__ out, int B)
{
  __shared__ __align__(16) float sc[168];
  const int tid = threadIdx.x;
  const int H = (B + 1) >> 1;
  const int t = blockIdx.x * 256 + tid;
  const int bA = t;
  const int bB = (t + H < B) ? (t + H) : (B - 1);

  float fA[22], fB[22];
  {
    const float2* pa = reinterpret_cast<const float2*>(feat + (size_t)bA * 22);
#pragma unroll
    for (int i = 0; i < 11; ++i) { const float2 v = pa[i]; fA[2 * i] = v.x; fA[2 * i + 1] = v.y; }
  }

  if (tid < 168) {
    const int pair = tid / 6;
    const int slot = tid % 6;
    const int w = slot / 3;
    const int pq = slot % 3;
    int U = 0, rem = pair;
#pragma unroll
    for (int uu = 0; uu < 7; ++uu)
      if (rem >= 7 - uu && U == uu) { rem -= 7 - uu; U = uu + 1; }
    const int V = U + 1 + rem;
    const int p = (pq == 2) ? 1 : 0; // pq: 0->(0,1), 1->(0,2), 2->(1,2)
    const int q = (pq == 0) ? 1 : 2;
    const float a1U = w46t[U] + w64t[U], a1V = w46t[V] + w64t[V];
    const float apU = (p == 0) ? w44t[U] : a1U;
    const float apV = (p == 0) ? w44t[V] : a1V;
    const float aqU = (q == 1) ? a1U : w66t[U];
    const float aqV = (q == 1) ? a1V : w66t[V];
    const float Aw = wtt[(U * 8 + V) * 2 + w] - wtt[(V * 8 + U) * 2 + w];
    sc[tid] = Aw * (apU * aqV - apV * aqU);
  }
  __syncthreads();

  // midLoad: called between A's 4x6 and 6x6 loops (f4A registers just died)
  auto loadB = [&]() __attribute__((always_inline)) {
    const float2* pb = reinterpret_cast<const float2*>(feat + (size_t)bB * 22);
#pragma unroll
    for (int i = 0; i < 11; ++i) { const float2 v = pb[i]; fB[2 * i] = v.x; fB[2 * i + 1] = v.y; }
  };
  auto noop = [&]() __attribute__((always_inline)) {};

  auto process = [&](const float* __restrict__ f, int b, auto midLoad) __attribute__((always_inline)) {
    const float* f4 = f;
    const float* f6 = f + 9;

    float q44 = 0.f, q66 = 0.f;
    float T0[5] = {}, T1[5] = {}, T2[5] = {}; // T44, T46(=T64), T66

    // ---- 4x4 ----
#pragma unroll
    for (int I = 0; I < 9; ++I)
#pragma unroll
      for (int J = I; J < 9; ++J) {
        const float p = f4[I] * f4[J];
        {
          const float c = (I == J) ? (float)cw::W440.v[I * 9 + J]
                                   : (float)(cw::W440.v[I * 9 + J] + cw::W440.v[J * 9 + I]);
          if (c != 0.f) q44 = fmaf(c, p, q44);
        }
#pragma unroll
        for (int K = 0; K < 5; ++K) {
          const float c = (I == J) ? (float)cw::W442.v[(I * 9 + J) * 5 + K]
                                   : (float)(cw::W442.v[(I * 9 + J) * 5 + K] + cw::W442.v[(J * 9 + I) * 5 + K]);
          if (c != 0.f) T0[K] = fmaf(c, p, T0[K]);
        }
      }

    // ---- 4x6 ----
#pragma unroll
    for (int a = 0; a < 9; ++a)
#pragma unroll
      for (int bb = 0; bb < 13; ++bb) {
        const float p = f4[a] * f6[bb];
#pragma unroll
        for (int K = 0; K < 5; ++K) {
          const float c46 = (float)cw::W462.v[(a * 13 + bb) * 5 + K];
          if (c46 != 0.f) T1[K] = fmaf(c46, p, T1[K]);
        }
      }

    midLoad(); // element A: issue fB loads here (f4 of A is dead now)

    // ---- 6x6 ----
#pragma unroll
    for (int I = 0; I < 13; ++I)
#pragma unroll
      for (int J = I; J < 13; ++J) {
        const float p = f6[I] * f6[J];
        {
          const float c = (I == J) ? (float)cw::W660.v[I * 13 + J]
                                   : (float)(cw::W660.v[I * 13 + J] + cw::W660.v[J * 13 + I]);
          if (c != 0.f) q66 = fmaf(c, p, q66);
        }
#pragma unroll
        for (int K = 0; K < 5; ++K) {
          const float c = (I == J) ? (float)cw::W662.v[(I * 13 + J) * 5 + K]
                                   : (float)(cw::W662.v[(I * 13 + J) * 5 + K] + cw::W662.v[(J * 13 + I) * 5 + K]);
          if (c != 0.f) T2[K] = fmaf(c, p, T2[K]);
        }
      }

    // gates g_u = sigmoid(C0 * (w44s2[8+u] q44 + w66s2[8+u] q66))
    float g[8];
#pragma unroll
    for (int u = 0; u < 8; ++u) {
      const float s = 0.70710678118654752f * fmaf(w44s2[8 + u], q44, w66s2[8 + u] * q66);
      g[u] = __builtin_amdgcn_rcpf(1.f + __expf(-s));
    }

    // S_w(pq) = sum_{u<v} sc[pair*6 + w*3 + pq] * g_u g_v  (float4 LDS reads)
    float S00 = 0.f, S01 = 0.f, S02 = 0.f, S10 = 0.f, S11 = 0.f, S12 = 0.f;
    {
      const float4* scv = reinterpret_cast<const float4*>(sc);
#pragma unroll
      for (int gp = 0; gp < 14; ++gp) {
        const float4 c0 = scv[gp * 3 + 0];
        const float4 c1 = scv[gp * 3 + 1];
        const float4 c2 = scv[gp * 3 + 2];
        const float Ga = g[cw::PP.u[2 * gp]] * g[cw::PP.v[2 * gp]];
        const float Gb = g[cw::PP.u[2 * gp + 1]] * g[cw::PP.v[2 * gp + 1]];
        S00 = fmaf(c0.x, Ga, S00); S01 = fmaf(c0.y, Ga, S01); S02 = fmaf(c0.z, Ga, S02);
        S10 = fmaf(c0.w, Ga, S10); S11 = fmaf(c1.x, Ga, S11); S12 = fmaf(c1.y, Ga, S12);
        S00 = fmaf(c1.z, Gb, S00); S01 = fmaf(c1.w, Gb, S01); S02 = fmaf(c2.x, Gb, S02);
        S10 = fmaf(c2.y, Gb, S10); S11 = fmaf(c2.z, Gb, S11); S12 = fmaf(c2.w, Gb, S12);
      }
    }

    // B_K(T_p,T_q): av_q = C221_K T_q (sparse), then dots
    float av1[3][5] = {}, av2[3][5] = {};
#pragma unroll
    for (int I = 0; I < 5; ++I)
#pragma unroll
      for (int J = 0; J < 5; ++J)
#pragma unroll
        for (int K = 0; K < 3; ++K) {
          const float c = (float)cw::W221.v[(I * 5 + J) * 3 + K];
          if (c != 0.f) {
            av1[K][I] = fmaf(c, T1[J], av1[K][I]);
            av2[K][I] = fmaf(c, T2[J], av2[K][I]);
          }
        }
    float v0[3], v1[3];
#pragma unroll
    for (int K = 0; K < 3; ++K) {
      float M0 = 0.f, M1 = 0.f, M2 = 0.f;
#pragma unroll
      for (int I = 0; I < 5; ++I) {
        M0 = fmaf(T0[I], av1[K][I], M0); // B_K(T0,T1)
        M1 = fmaf(T0[I], av2[K][I], M1); // B_K(T0,T2)
        M2 = fmaf(T1[I], av2[K][I], M2); // B_K(T1,T2)
      }
      v0[K] = fmaf(M0, S00, fmaf(M1, S01, M2 * S02));
      v1[K] = fmaf(M0, S10, fmaf(M1, S11, M2 * S12));
    }

    // Gram-Schmidt frame (rsq on squared norms)
    const float nsq0 = v0[0] * v0[0] + v0[1] * v0[1] + v0[2] * v0[2];
    const float i0 = __builtin_amdgcn_rsqf(fmaxf(nsq0, 1e-12f));
    const float z0 = v0[0] * i0, z1 = v0[1] * i0, z2 = v0[2] * i0;
    const float dot = z0 * v1[0] + z1 * v1[1] + z2 * v1[2];
    const float xv0 = v1[0] - dot * z0, xv1 = v1[1] - dot * z1, xv2 = v1[2] - dot * z2;
    const float nsqx = xv0 * xv0 + xv1 * xv1 + xv2 * xv2;
    const float ix = __builtin_amdgcn_rsqf(fmaxf(nsqx, 1e-12f));
    const float x0 = xv0 * ix, x1 = xv1 * ix, x2 = xv2 * ix;
    const float y0 = z1 * x2 - z2 * x1;
    const float y1 = z2 * x0 - z0 * x2;
    const float y2 = z0 * x1 - z1 * x0;

    // beta = acos(clamp(z2)) via 4-term poly (|err|<=6.7e-5 rad)
    const float r22 = fminf(fmaxf(z2, -1.f), 1.f);
    const float axr = fabsf(r22);
    const float bp = fmaf(axr, fmaf(axr, fmaf(axr, -0.0187293f, 0.0742610f), -0.2121144f), 1.5707288f);
    const float bac = sqrtf(fmaxf(1.f - axr, 0.f)) * bp;
    const float beta = (r22 < 0.f) ? 3.14159274f - bac : bac;

    const bool safe = axr < 1.0f;
    float alpha = fatan2(z1, z0);
    float gamma = fatan2(y2, -x2);
    if (__ballot(!safe)) {
      if (!safe) { alpha = 0.f; gamma = fatan2(-y0, y1); }
    }

    if (b < B) {
      out[b] = alpha;
      out[B + b] = beta;
      out[2 * (size_t)B + b] = gamma;
      float* Ro = out + 3 * (size_t)B + (size_t)b * 9;
      Ro[0] = x0; Ro[1] = y0; Ro[2] = z0;
      Ro[3] = x1; Ro[4] = y1; Ro[5] = z1;
      Ro[6] = x2; Ro[7] = y2; Ro[8] = z2;
    }
  };

  process(fA, bA, loadB);
  if (t + H < B) process(fB, t + H, noop);
}

extern "C" void kernel_launch(void* const* d_in, const int* in_sizes, int n_in,
                              void* d_out, int out_size, void* d_ws, size_t ws_size,
                              hipStream_t stream) {
  (void)n_in; (void)out_size; (void)d_ws; (void)ws_size;
  const float* feat  = (const float*)d_in[0];
  const float* w44s2 = (const float*)d_in[3];
  const float* w66s2 = (const float*)d_in[4];
  const float* w44t  = (const float*)d_in[7];
  const float* w46t  = (const float*)d_in[8];
  const float* w64t  = (const float*)d_in[9];
  const float* w66t  = (const float*)d_in[10];
  const float* wtt   = (const float*)d_in[16];
  float* out = (float*)d_out;
  const int B = in_sizes[0] / 22;
  const int H = (B + 1) >> 1;
  geo_euler<<<(H + 255) / 256, 256, 0, stream>>>(feat, w44s2, w66s2,
                                                 w44t, w46t, w64t, w66t, wtt, out, B);
}